// Round 8
// baseline (1070.924 us; speedup 1.0000x reference)
//
#include <hip/hip_runtime.h>
#include <hip/hip_bf16.h>

using bf16x8 = __attribute__((ext_vector_type(8))) short;
using f32x4  = __attribute__((ext_vector_type(4))) float;

#define FS_CHUNK 4096

// ---------- helpers ----------
__device__ __forceinline__ float ldf(const void* p, size_t i, float isf){
  if (isf > 0.5f) return ((const float*)p)[i];
  unsigned int u = ((unsigned int)((const unsigned short*)p)[i]) << 16;
  return __uint_as_float(u);
}
__device__ __forceinline__ unsigned short f2bf(float v){
  unsigned int u = __float_as_uint(v);
  u = (u + 0x7FFFu + ((u >> 16) & 1u)) >> 16;   // RNE
  return (unsigned short)u;
}
__device__ __forceinline__ unsigned int pk2(float a, float b){
  return (unsigned int)f2bf(a) | ((unsigned int)f2bf(b) << 16);
}
__device__ __forceinline__ float lo16(unsigned int u){ return __uint_as_float(u << 16); }
__device__ __forceinline__ float hi16(unsigned int u){ return __uint_as_float(u & 0xFFFF0000u); }

// load 8 CSR indices with one (u16) or two (int) vector loads; p must be 16B-aligned
template<typename IT>
__device__ __forceinline__ void load8idx(const IT* p, int* o){
  if (sizeof(IT) == 2){
    uint4 v = *(const uint4*)p;
    o[0] = (int)(v.x & 0xFFFFu); o[1] = (int)(v.x >> 16);
    o[2] = (int)(v.y & 0xFFFFu); o[3] = (int)(v.y >> 16);
    o[4] = (int)(v.z & 0xFFFFu); o[5] = (int)(v.z >> 16);
    o[6] = (int)(v.w & 0xFFFFu); o[7] = (int)(v.w >> 16);
  } else {
    int4 a = ((const int4*)p)[0];
    int4 c = ((const int4*)p)[1];
    o[0]=a.x; o[1]=a.y; o[2]=a.z; o[3]=a.w;
    o[4]=c.x; o[5]=c.y; o[6]=c.z; o[7]=c.w;
  }
}

__global__ void k_fill(unsigned short* o, unsigned short v, int n){
  int i = blockIdx.x*blockDim.x + threadIdx.x;
  if (i < n) o[i] = v;
}

// ---------- fused: dtype detect + weight convert (block 0) + zero cnt/st/gctr/bhist/HSrowN ----------
__global__ void k_prep(const unsigned short* xh, const unsigned int* eu,
                       float* flag, int nelemX, long long E,
                       const void* W1, const void* W2, const void* W3, const void* W4,
                       unsigned short* __restrict__ Wt1, unsigned short* __restrict__ Wt2,
                       unsigned short* __restrict__ Wt3, float* __restrict__ W4f,
                       int* __restrict__ cnt, float* __restrict__ stAll,
                       unsigned short* __restrict__ HS, int n){
  int t = threadIdx.x;
  if (blockIdx.x > 0){
    if (blockIdx.x == 1 && t < 96) HS[(size_t)96*n + t] = 0;   // zero row n (dummy gather target)
    int total = n + 4676;                 // cnt[N] + stats/gctr/pad + bhist(64)
    for (int i = (int)(blockIdx.x-1)*256 + t; i < total; i += (int)(gridDim.x-1)*256){
      if (i < n) cnt[i] = 0; else stAll[i - n] = 0.f;   // 0.0f bits == int 0
    }
    return;
  }
  __shared__ int sf32, si64;
  __shared__ float sisf;
  if (t == 0){ sf32 = 0; si64 = 1; }
  __syncthreads();
  {
    int i = 2*t;
    if (i < nelemX){
      unsigned e8 = (xh[i] >> 7) & 0xFFu;
      if (e8 >= 140u) sf32 = 1;
    }
    if ((long long)(2*t + 1) < 2*E){
      if (eu[2*t + 1] != 0u) si64 = 0;
    }
  }
  __syncthreads();
  if (t == 0){
    flag[0] = (float)sf32; flag[1] = (float)si64;
    sisf = (float)sf32;
  }
  __syncthreads();
  float isf = sisf;
  for (int q = t; q < 3072; q += 256){
    int nn = q >> 5, k = q & 31;
    Wt1[q] = f2bf(ldf(W1, (size_t)96*k + nn, isf));
  }
  for (int q = t; q < 9216; q += 256){
    int nn = q/96, k = q - 96*nn;
    Wt2[q] = f2bf(ldf(W2, (size_t)96*k + nn, isf));
    Wt3[q] = f2bf(ldf(W3, (size_t)96*k + nn, isf));
  }
  if (t < 192) W4f[t] = ldf(W4, t, isf);
}

// ---------- degree count + edge compaction, u16-PACKED (dst<<16 | src), 4B/edge ----------
__global__ void k_cnt2p(const int* __restrict__ ei, const float* __restrict__ flag,
                        int* __restrict__ cnt, unsigned int* __restrict__ ec,
                        long long E, int n){
  long long i = (long long)blockIdx.x*blockDim.x + threadIdx.x;  // handles edges 2i, 2i+1
  long long i0 = 2*i;
  if (i0 >= E) return;
  bool i64 = (flag[1] > 0.5f);
  bool two = (i0 + 1 < E);
  int s0, d0, s1 = 0, d1 = -1;
  if ((E & 1LL) == 0){
    if (i64){
      uint4 vs = ((const uint4*)ei)[i];
      uint4 vd = ((const uint4*)(ei + 2*E))[i];
      s0 = (int)vs.x; s1 = (int)vs.z; d0 = (int)vd.x; d1 = (int)vd.z;
    } else {
      int2 vs = ((const int2*)ei)[i];
      int2 vd = ((const int2*)(ei + E))[i];
      s0 = vs.x; s1 = vs.y; d0 = vd.x; d1 = vd.y;
    }
  } else {
    if (i64){ s0 = ei[2*i0]; d0 = ei[2*E + 2*i0];
              if (two){ s1 = ei[2*i0+2]; d1 = ei[2*E + 2*i0 + 2]; } }
    else    { s0 = ei[i0];   d0 = ei[E + i0];
              if (two){ s1 = ei[i0+1];   d1 = ei[E + i0 + 1]; } }
  }
  bool ok0 = ((unsigned)s0 < (unsigned)n) && ((unsigned)d0 < (unsigned)n);
  bool ok1 = two && ((unsigned)s1 < (unsigned)n) && ((unsigned)d1 < (unsigned)n);
  unsigned p0 = ok0 ? (((unsigned)d0 << 16) | (unsigned)s0) : 0xFFFFFFFFu;
  unsigned p1 = ok1 ? (((unsigned)d1 << 16) | (unsigned)s1) : 0xFFFFFFFFu;
  if (two){
    uint2 o; o.x = p0; o.y = p1;
    ((uint2*)ec)[i] = o;
  } else {
    ec[i0] = p0;
  }
  if (ok0) atomicAdd(&cnt[d0], 1);
  if (ok1) atomicAdd(&cnt[d1], 1);
}

// ---------- degree count + edge compaction, int pairs (big-N path) ----------
__global__ void k_cnt2(const int* __restrict__ ei, const float* __restrict__ flag,
                       int* __restrict__ cnt, int* __restrict__ ec,
                       long long E, int n){
  long long i = (long long)blockIdx.x*blockDim.x + threadIdx.x;
  long long i0 = 2*i;
  if (i0 >= E) return;
  bool i64 = (flag[1] > 0.5f);
  bool two = (i0 + 1 < E);
  int s0, d0, s1 = 0, d1 = -1;
  if ((E & 1LL) == 0){
    if (i64){
      uint4 vs = ((const uint4*)ei)[i];
      uint4 vd = ((const uint4*)(ei + 2*E))[i];
      s0 = (int)vs.x; s1 = (int)vs.z; d0 = (int)vd.x; d1 = (int)vd.z;
    } else {
      int2 vs = ((const int2*)ei)[i];
      int2 vd = ((const int2*)(ei + E))[i];
      s0 = vs.x; s1 = vs.y; d0 = vd.x; d1 = vd.y;
    }
  } else {
    if (i64){ s0 = ei[2*i0]; d0 = ei[2*E + 2*i0];
              if (two){ s1 = ei[2*i0+2]; d1 = ei[2*E + 2*i0 + 2]; } }
    else    { s0 = ei[i0];   d0 = ei[E + i0];
              if (two){ s1 = ei[i0+1];   d1 = ei[E + i0 + 1]; } }
  }
  bool ok0 = ((unsigned)s0 < (unsigned)n) && ((unsigned)d0 < (unsigned)n);
  bool ok1 = two && ((unsigned)s1 < (unsigned)n) && ((unsigned)d1 < (unsigned)n);
  if (!ok0){ s0 = -1; d0 = -1; }
  if (!ok1){ s1 = -1; d1 = -1; }
  if (two){
    int4 o; o.x = s0; o.y = d0; o.z = s1; o.w = d1;
    ((int4*)ec)[i] = o;
  } else {
    int2 o; o.x = s0; o.y = d0;
    ((int2*)ec)[i0] = o;
  }
  if (ok0) atomicAdd(&cnt[d0], 1);
  if (ok1) atomicAdd(&cnt[d1], 1);
}

// ---------- row allocation (deg rounded to mult of 8) + degree-bucket histogram ----------
template<typename IT>
__global__ void k_emit2(const int* __restrict__ cnt, int* __restrict__ gctr,
                        int* __restrict__ rowst, int* __restrict__ cursor,
                        float* __restrict__ dinv, IT* __restrict__ csr,
                        int* __restrict__ bhist, int n){
  int i = blockIdx.x*256 + threadIdx.x;
  int lane = threadIdx.x & 63;
  int v  = (i < n) ? cnt[i] : 0;
  int rv = (v + 7) & ~7;                  // rounded allocation
  int s = rv;
  #pragma unroll
  for (int off = 1; off < 64; off <<= 1){
    int u = __shfl_up(s, off, 64);
    if (lane >= off) s += u;
  }
  int wtot = __shfl(s, 63, 64);
  int base = 0;
  if (lane == 63) base = atomicAdd(gctr, wtot);
  base = __shfl(base, 63, 64);
  if (i < n){
    int r = base + s - rv;
    rowst[i]  = r;
    cursor[i] = r;
    dinv[i]   = rsqrtf((float)(1 + v));
    for (int p = r + v; p < r + rv; ++p) csr[p] = (IT)n;   // dummy -> zero row
    int bk = rv >> 3; if (bk > 63) bk = 63;
    atomicAdd(&bhist[bk], 1);
  }
}

// ---------- bucket prefix: 64 buckets, one wave ----------
__global__ void k_bpre(const int* __restrict__ bhist, int* __restrict__ bcur){
  int t = threadIdx.x;                    // 64 threads, one wave
  int h = bhist[t];
  int s = h;
  #pragma unroll
  for (int off = 1; off < 64; off <<= 1){
    int u = __shfl_up(s, off, 64);
    if (t >= off) s += u;
  }
  bcur[t] = s - h;                        // exclusive base; serves as scatter cursor
}

// ---------- merged: CSR slot fill (packed ec) + XS build + degree-sorted perm scatter ----------
__global__ __launch_bounds__(256) void k_fxp(const unsigned int* __restrict__ ec,
      int* __restrict__ cursor, unsigned short* __restrict__ csr,
      long long E, int n, int gF8, int gXS,
      const void* __restrict__ x, const float* __restrict__ flag,
      const float* __restrict__ dinv, unsigned short* __restrict__ XS,
      const int* __restrict__ cnt, int* __restrict__ bcur, int* __restrict__ perm){
  int t = threadIdx.x;
  if ((int)blockIdx.x < gF8){
    int part = blockIdx.x & 7;
    long long base = (long long)(blockIdx.x >> 3) * FS_CHUNK;
    int pl = (int)(((long long)n *  part     ) >> 3);
    int pr = (int)(((long long)n * (part + 1)) >> 3);
    long long lim = base + FS_CHUNK < E ? base + FS_CHUNK : E;
    for (long long i = base + 4*t; i < lim; i += 1024){
      uint4 v = ((const uint4*)ec)[i >> 2];          // edges i..i+3 packed (dst<<16|src)
      { int d = (int)(v.x >> 16);
        if (d >= pl && d < pr){ int p = atomicAdd(&cursor[d], 1); csr[p] = (unsigned short)(v.x & 0xFFFFu); } }
      if (i + 1 < lim){ int d = (int)(v.y >> 16);
        if (d >= pl && d < pr){ int p = atomicAdd(&cursor[d], 1); csr[p] = (unsigned short)(v.y & 0xFFFFu); } }
      if (i + 2 < lim){ int d = (int)(v.z >> 16);
        if (d >= pl && d < pr){ int p = atomicAdd(&cursor[d], 1); csr[p] = (unsigned short)(v.z & 0xFFFFu); } }
      if (i + 3 < lim){ int d = (int)(v.w >> 16);
        if (d >= pl && d < pr){ int p = atomicAdd(&cursor[d], 1); csr[p] = (unsigned short)(v.w & 0xFFFFu); } }
    }
    return;
  }
  if ((int)blockIdx.x < gF8 + gXS){
    int q = (int)(blockIdx.x - gF8)*256 + t;
    if (q < 4*(n+1)){
      int node = q >> 2, part = q & 3;
      uint4 o;
      if (node < n){
        float isf = flag[0];
        float di = dinv[node];
        if (isf > 0.5f){
          const float* xr = (const float*)x + (size_t)32*node + 8*part;
          o.x = pk2(xr[0]*di, xr[1]*di); o.y = pk2(xr[2]*di, xr[3]*di);
          o.z = pk2(xr[4]*di, xr[5]*di); o.w = pk2(xr[6]*di, xr[7]*di);
        } else {
          uint4 v = ((const uint4*)x)[(size_t)4*node + part];
          o.x = pk2(lo16(v.x)*di, hi16(v.x)*di);
          o.y = pk2(lo16(v.y)*di, hi16(v.y)*di);
          o.z = pk2(lo16(v.z)*di, hi16(v.z)*di);
          o.w = pk2(lo16(v.w)*di, hi16(v.w)*di);
        }
      } else { o.x = o.y = o.z = o.w = 0u; }        // zero row n (dummy gather target)
      ((uint4*)XS)[q] = o;
    }
    return;
  }
  // perm scatter: degree-bucket sort of node ids
  int i = (int)(blockIdx.x - gF8 - gXS)*256 + t;
  if (i < n){
    int bk = ((cnt[i] + 7) & ~7) >> 3; if (bk > 63) bk = 63;
    int pos = atomicAdd(&bcur[bk], 1);
    perm[pos] = i;
  }
}

// ---------- merged fill + XS + perm, int path (big N) ----------
__global__ __launch_bounds__(256) void k_fx(const int* __restrict__ ec,
      int* __restrict__ cursor, int* __restrict__ csr,
      long long E, int n, int gF8, int gXS,
      const void* __restrict__ x, const float* __restrict__ flag,
      const float* __restrict__ dinv, unsigned short* __restrict__ XS,
      const int* __restrict__ cnt, int* __restrict__ bcur, int* __restrict__ perm){
  int t = threadIdx.x;
  if ((int)blockIdx.x < gF8){
    int part = blockIdx.x & 7;
    long long base = (long long)(blockIdx.x >> 3) * FS_CHUNK;
    int pl = (int)(((long long)n *  part     ) >> 3);
    int pr = (int)(((long long)n * (part + 1)) >> 3);
    long long lim = base + FS_CHUNK < E ? base + FS_CHUNK : E;
    for (long long i = base + 2*t; i < lim; i += 512){
      int4 v = ((const int4*)ec)[i >> 1];
      if (v.y >= pl && v.y < pr && (unsigned)v.x < (unsigned)n){
        int p = atomicAdd(&cursor[v.y], 1);
        csr[p] = v.x;
      }
      if (i + 1 < lim && v.w >= pl && v.w < pr && (unsigned)v.z < (unsigned)n){
        int p = atomicAdd(&cursor[v.w], 1);
        csr[p] = v.z;
      }
    }
    return;
  }
  if ((int)blockIdx.x < gF8 + gXS){
    int q = (int)(blockIdx.x - gF8)*256 + t;
    if (q < 4*(n+1)){
      int node = q >> 2, part = q & 3;
      uint4 o;
      if (node < n){
        float isf = flag[0];
        float di = dinv[node];
        if (isf > 0.5f){
          const float* xr = (const float*)x + (size_t)32*node + 8*part;
          o.x = pk2(xr[0]*di, xr[1]*di); o.y = pk2(xr[2]*di, xr[3]*di);
          o.z = pk2(xr[4]*di, xr[5]*di); o.w = pk2(xr[6]*di, xr[7]*di);
        } else {
          uint4 v = ((const uint4*)x)[(size_t)4*node + part];
          o.x = pk2(lo16(v.x)*di, hi16(v.x)*di);
          o.y = pk2(lo16(v.y)*di, hi16(v.y)*di);
          o.z = pk2(lo16(v.z)*di, hi16(v.z)*di);
          o.w = pk2(lo16(v.w)*di, hi16(v.w)*di);
        }
      } else { o.x = o.y = o.z = o.w = 0u; }
      ((uint4*)XS)[q] = o;
    }
    return;
  }
  int i = (int)(blockIdx.x - gF8 - gXS)*256 + t;
  if (i < n){
    int bk = ((cnt[i] + 7) & ~7) >> 3; if (bk > 63) bk = 63;
    int pos = atomicAdd(&bcur[bk], 1);
    perm[pos] = i;
  }
}

#define ACC8(v) { a0+=lo16((v).x); a1+=hi16((v).x); a2+=lo16((v).y); a3+=hi16((v).y); \
                  a4+=lo16((v).z); a5+=hi16((v).z); a6+=lo16((v).w); a7+=hi16((v).w); }

// ---------- layer 1: degree-sorted gather-sum XS + dinv + MFMA W1 + stats ----------
template<typename IT>
__global__ __launch_bounds__(256) void k_aggx(const uint4* __restrict__ xs4,
      const int* __restrict__ rowst, const int* __restrict__ cnt,
      const IT* __restrict__ csr, const int* __restrict__ perm,
      const float* __restrict__ dinv,
      const unsigned short* __restrict__ Wt1b,
      unsigned short* __restrict__ Zb, float* __restrict__ stout, int n){
  __shared__ __align__(16) unsigned short Xs[64][40];
  __shared__ __align__(16) unsigned short Wt[96][40];
  __shared__ float bs[96], bq[96];
  int t = threadIdx.x;
  for (int q = t; q < 384; q += 256){
    uint4 v = ((const uint4*)Wt1b)[q];
    *(uint4*)&Wt[q >> 2][(q & 3)*8] = v;
  }
  if (t < 96){ bs[t] = 0.f; bq[t] = 0.f; }
  int g = t & 3, ty = t >> 2;
  int idx = blockIdx.x*64 + ty;
  int node = (idx < n) ? perm[idx] : -1;
  float a0=0.f,a1=0.f,a2=0.f,a3=0.f,a4=0.f,a5=0.f,a6=0.f,a7=0.f;
  if (node >= 0){
    uint4 v = xs4[(size_t)node*4 + g];           // self-loop contribution
    ACC8(v);
    int bq_ = rowst[node];
    int bnd = bq_ + ((cnt[node] + 7) & ~7);      // padded, uniform batches of 8
    for (int j = bq_; j < bnd; j += 8){
      int ix[8];
      load8idx<IT>(csr + j, ix);
      uint4 v0 = xs4[(size_t)ix[0]*4 + g];
      uint4 v1 = xs4[(size_t)ix[1]*4 + g];
      uint4 v2 = xs4[(size_t)ix[2]*4 + g];
      uint4 v3 = xs4[(size_t)ix[3]*4 + g];
      uint4 v4 = xs4[(size_t)ix[4]*4 + g];
      uint4 v5 = xs4[(size_t)ix[5]*4 + g];
      uint4 v6 = xs4[(size_t)ix[6]*4 + g];
      uint4 v7 = xs4[(size_t)ix[7]*4 + g];
      ACC8(v0); ACC8(v1); ACC8(v2); ACC8(v3);
      ACC8(v4); ACC8(v5); ACC8(v6); ACC8(v7);
    }
    float di = dinv[node];
    a0*=di; a1*=di; a2*=di; a3*=di; a4*=di; a5*=di; a6*=di; a7*=di;
  }
  uint4 o;
  o.x = pk2(a0,a1); o.y = pk2(a2,a3); o.z = pk2(a4,a5); o.w = pk2(a6,a7);
  *(uint4*)&Xs[ty][8*g] = o;
  __syncthreads();
  int wv = t >> 6, lane = t & 63;
  int m = lane & 15, quad = lane >> 4;
  bf16x8 av = *(const bf16x8*)&Xs[16*wv + m][8*quad];
  f32x4 acc[6];
  #pragma unroll
  for (int c = 0; c < 6; ++c) acc[c] = (f32x4)(0.f);
  #pragma unroll
  for (int c = 0; c < 6; ++c){
    bf16x8 bv = *(const bf16x8*)&Wt[16*c + m][8*quad];
    acc[c] = __builtin_amdgcn_mfma_f32_16x16x32_bf16(av, bv, acc[c], 0, 0, 0);
  }
  int rowbase = blockIdx.x*64 + 16*wv + 4*quad;
  int nw[4];
  #pragma unroll
  for (int r = 0; r < 4; ++r){ int ii = rowbase + r; nw[r] = (ii < n) ? perm[ii] : -1; }
  #pragma unroll
  for (int c = 0; c < 6; ++c){
    int col = 16*c + m;
    float s = 0.f, q = 0.f;
    #pragma unroll
    for (int r = 0; r < 4; ++r){
      if (nw[r] >= 0){
        unsigned short h = f2bf(acc[c][r]);
        Zb[(size_t)96*nw[r] + col] = h;
        float br = __uint_as_float(((unsigned int)h) << 16);
        s += br; q += br*br;
      }
    }
    atomicAdd(&bs[col], s);
    atomicAdd(&bq[col], q);
  }
  __syncthreads();
  if (t < 96){
    int rep = blockIdx.x & 7;
    atomicAdd(&stout[192*rep + t],      bs[t]);
    atomicAdd(&stout[192*rep + 96 + t], bq[t]);
  }
}

// ---------- degree-sorted CSR gather aggregation (96 cols) + fused BN stats ----------
template<typename IT>
__global__ __launch_bounds__(192) void k_agg(const uint4* __restrict__ hsr,
      const int* __restrict__ rowst, const int* __restrict__ cnt,
      const IT* __restrict__ csr, const int* __restrict__ perm,
      const float* __restrict__ dinv, uint4* __restrict__ zb4,
      float* __restrict__ stout, int n){
  __shared__ float ls[16][97], lq[16][97];
  int g = threadIdx.x, ty = threadIdx.y;
  int t = ty*12 + g;
  int idx = blockIdx.x*16 + ty;
  int node = (idx < n) ? perm[idx] : -1;
  float r[8];
  if (node >= 0){
    uint4 v = hsr[(size_t)node*12 + g];
    float a0 = lo16(v.x), a1 = hi16(v.x), a2 = lo16(v.y), a3 = hi16(v.y);
    float a4 = lo16(v.z), a5 = hi16(v.z), a6 = lo16(v.w), a7 = hi16(v.w);
    int bq_ = rowst[node];
    int bnd = bq_ + ((cnt[node] + 7) & ~7);      // padded, uniform batches of 8
    for (int j = bq_; j < bnd; j += 8){
      int ix[8];
      load8idx<IT>(csr + j, ix);
      uint4 v0 = hsr[(size_t)ix[0]*12 + g];
      uint4 v1 = hsr[(size_t)ix[1]*12 + g];
      uint4 v2 = hsr[(size_t)ix[2]*12 + g];
      uint4 v3 = hsr[(size_t)ix[3]*12 + g];
      uint4 v4 = hsr[(size_t)ix[4]*12 + g];
      uint4 v5 = hsr[(size_t)ix[5]*12 + g];
      uint4 v6 = hsr[(size_t)ix[6]*12 + g];
      uint4 v7 = hsr[(size_t)ix[7]*12 + g];
      ACC8(v0); ACC8(v1); ACC8(v2); ACC8(v3);
      ACC8(v4); ACC8(v5); ACC8(v6); ACC8(v7);
    }
    float di = dinv[node];
    uint4 o;
    o.x = pk2(a0*di, a1*di);
    o.y = pk2(a2*di, a3*di);
    o.z = pk2(a4*di, a5*di);
    o.w = pk2(a6*di, a7*di);
    zb4[(size_t)node*12 + g] = o;
    r[0]=lo16(o.x); r[1]=hi16(o.x); r[2]=lo16(o.y); r[3]=hi16(o.y);
    r[4]=lo16(o.z); r[5]=hi16(o.z); r[6]=lo16(o.w); r[7]=hi16(o.w);
  } else {
    #pragma unroll
    for (int jj = 0; jj < 8; ++jj) r[jj] = 0.f;
  }
  #pragma unroll
  for (int jj = 0; jj < 8; ++jj){
    ls[ty][8*g + jj] = r[jj];
    lq[ty][8*g + jj] = r[jj]*r[jj];
  }
  __syncthreads();
  if (t < 96){
    float s = 0.f, q = 0.f;
    #pragma unroll
    for (int rr = 0; rr < 16; ++rr){ s += ls[rr][t]; q += lq[rr][t]; }
    int rep = blockIdx.x & 7;
    atomicAdd(&stout[192*rep + t],      s);
    atomicAdd(&stout[192*rep + 96 + t], q);
  }
}

// ---------- MFMA mid layer ----------
__global__ __launch_bounds__(256) void k_linm(const unsigned short* __restrict__ zb,
      const unsigned short* __restrict__ Wtb, const float* __restrict__ st,
      const void* __restrict__ gam, const void* __restrict__ bet,
      const float* __restrict__ flag, const float* __restrict__ dinv,
      unsigned short* __restrict__ HS, int n, float invN){
  __shared__ float sa[96], sc[96];
  __shared__ __align__(16) unsigned short Ys[64][104];
  __shared__ __align__(16) unsigned short Wt[96][104];
  int t = threadIdx.x;
  if (t < 96){
    float ssum = 0.f, qsum = 0.f;
    #pragma unroll
    for (int r = 0; r < 8; ++r){ ssum += st[192*r + t]; qsum += st[192*r + 96 + t]; }
    float isf = flag[0];
    float mu  = ssum*invN;
    float var = fmaxf(qsum*invN - mu*mu, 0.f);
    float istd = rsqrtf(var + 1e-5f);
    float a = ldf(gam, t, isf)*istd;
    sa[t] = a; sc[t] = ldf(bet, t, isf) - mu*a;
  }
  for (int q = t; q < 1152; q += 256){
    uint4 v = ((const uint4*)Wtb)[q];
    *(uint4*)&Wt[q/12][8*(q - 12*(q/12))] = v;
  }
  __syncthreads();
  {
    int row = t >> 2, part = t & 3;
    int node = blockIdx.x*64 + row;
    if (node < n){
      const uint4* zr = (const uint4*)(zb + (size_t)96*node) + 3*part;
      #pragma unroll
      for (int q = 0; q < 3; ++q){
        uint4 zz = zr[q];
        int k = 24*part + 8*q;
        float y0 = fmaxf(lo16(zz.x)*sa[k]   + sc[k],   0.f);
        float y1 = fmaxf(hi16(zz.x)*sa[k+1] + sc[k+1], 0.f);
        float y2 = fmaxf(lo16(zz.y)*sa[k+2] + sc[k+2], 0.f);
        float y3 = fmaxf(hi16(zz.y)*sa[k+3] + sc[k+3], 0.f);
        float y4 = fmaxf(lo16(zz.z)*sa[k+4] + sc[k+4], 0.f);
        float y5 = fmaxf(hi16(zz.z)*sa[k+5] + sc[k+5], 0.f);
        float y6 = fmaxf(lo16(zz.w)*sa[k+6] + sc[k+6], 0.f);
        float y7 = fmaxf(hi16(zz.w)*sa[k+7] + sc[k+7], 0.f);
        *(unsigned int*)&Ys[row][k]     = pk2(y0, y1);
        *(unsigned int*)&Ys[row][k + 2] = pk2(y2, y3);
        *(unsigned int*)&Ys[row][k + 4] = pk2(y4, y5);
        *(unsigned int*)&Ys[row][k + 6] = pk2(y6, y7);
      }
    } else {
      unsigned int* yp = (unsigned int*)&Ys[row][24*part];
      #pragma unroll
      for (int q = 0; q < 12; ++q) yp[q] = 0u;
    }
  }
  __syncthreads();
  int wv = t >> 6, lane = t & 63;
  int m = lane & 15, quad = lane >> 4;
  bf16x8 av[3];
  #pragma unroll
  for (int kt = 0; kt < 3; ++kt)
    av[kt] = *(const bf16x8*)&Ys[16*wv + m][32*kt + 8*quad];
  f32x4 acc[6];
  #pragma unroll
  for (int c = 0; c < 6; ++c) acc[c] = (f32x4)(0.f);
  #pragma unroll
  for (int c = 0; c < 6; ++c){
    const unsigned short* wrow = &Wt[16*c + m][8*quad];
    #pragma unroll
    for (int kt = 0; kt < 3; ++kt){
      bf16x8 bv = *(const bf16x8*)(wrow + 32*kt);
      acc[c] = __builtin_amdgcn_mfma_f32_16x16x32_bf16(av[kt], bv, acc[c], 0, 0, 0);
    }
  }
  int rowbase = blockIdx.x*64 + 16*wv + 4*quad;
  float div[4];
  #pragma unroll
  for (int r = 0; r < 4; ++r){ int rr = rowbase + r; div[r] = (rr < n) ? dinv[rr] : 0.f; }
  #pragma unroll
  for (int c = 0; c < 6; ++c){
    int col = 16*c + m;
    #pragma unroll
    for (int r = 0; r < 4; ++r){
      int rr = rowbase + r;
      if (rr < n) HS[(size_t)96*rr + col] = f2bf(acc[c][r]*div[r]);
    }
  }
}

// ---------- layer 4 (96->2, VALU) ----------
__global__ __launch_bounds__(256) void k_lin4(const unsigned short* __restrict__ zb,
      const float* __restrict__ Wf, const float* __restrict__ st,
      const void* __restrict__ gam, const void* __restrict__ bet,
      const float* __restrict__ flag, const float* __restrict__ dinv,
      float* __restrict__ hs2, int n, float invN){
  __shared__ float sa[96], sc[96];
  int t = threadIdx.x;
  if (t < 96){
    float ssum = 0.f, qsum = 0.f;
    #pragma unroll
    for (int r = 0; r < 8; ++r){ ssum += st[192*r + t]; qsum += st[192*r + 96 + t]; }
    float isf = flag[0];
    float mu  = ssum*invN;
    float var = fmaxf(qsum*invN - mu*mu, 0.f);
    float istd = rsqrtf(var + 1e-5f);
    float a = ldf(gam, t, isf)*istd;
    sa[t] = a; sc[t] = ldf(bet, t, isf) - mu*a;
  }
  __syncthreads();
  int i = blockIdx.x*blockDim.x + t;
  if (i >= n) return;
  const uint4* zr = (const uint4*)(zb + (size_t)96*i);
  float a0 = 0.f, a1 = 0.f;
  #pragma unroll
  for (int q = 0; q < 12; ++q){
    uint4 zz = zr[q];
    int k = 8*q;
    float y;
    y = fmaxf(lo16(zz.x)*sa[k]   + sc[k],   0.f); a0 += y*Wf[2*k];    a1 += y*Wf[2*k+1];
    y = fmaxf(hi16(zz.x)*sa[k+1] + sc[k+1], 0.f); a0 += y*Wf[2*k+2];  a1 += y*Wf[2*k+3];
    y = fmaxf(lo16(zz.y)*sa[k+2] + sc[k+2], 0.f); a0 += y*Wf[2*k+4];  a1 += y*Wf[2*k+5];
    y = fmaxf(hi16(zz.y)*sa[k+3] + sc[k+3], 0.f); a0 += y*Wf[2*k+6];  a1 += y*Wf[2*k+7];
    y = fmaxf(lo16(zz.z)*sa[k+4] + sc[k+4], 0.f); a0 += y*Wf[2*k+8];  a1 += y*Wf[2*k+9];
    y = fmaxf(hi16(zz.z)*sa[k+5] + sc[k+5], 0.f); a0 += y*Wf[2*k+10]; a1 += y*Wf[2*k+11];
    y = fmaxf(lo16(zz.w)*sa[k+6] + sc[k+6], 0.f); a0 += y*Wf[2*k+12]; a1 += y*Wf[2*k+13];
    y = fmaxf(hi16(zz.w)*sa[k+7] + sc[k+7], 0.f); a0 += y*Wf[2*k+14]; a1 += y*Wf[2*k+15];
  }
  float di = dinv[i];
  hs2[(size_t)2*i]   = di*a0;
  hs2[(size_t)2*i+1] = di*a1;
}

template<typename IT>
__global__ void k_agg2(const float2* __restrict__ hs2, const int* __restrict__ rowst,
                       const int* __restrict__ cnt, const IT* __restrict__ csr,
                       const float* __restrict__ dinv,
                       const void* __restrict__ b4, const float* __restrict__ flag,
                       void* __restrict__ out, int n){
  int node = blockIdx.x*blockDim.x + threadIdx.x;
  if (node >= n) return;
  float2 a = hs2[node];
  int b = rowst[node], e = b + cnt[node];   // real count only (no padded reads)
  int j = b;
  for (; j + 3 < e; j += 4){
    float2 v0 = hs2[(size_t)csr[j]];
    float2 v1 = hs2[(size_t)csr[j+1]];
    float2 v2 = hs2[(size_t)csr[j+2]];
    float2 v3 = hs2[(size_t)csr[j+3]];
    a.x += v0.x + v1.x + v2.x + v3.x;
    a.y += v0.y + v1.y + v2.y + v3.y;
  }
  for (; j < e; ++j){
    float2 v = hs2[(size_t)csr[j]];
    a.x += v.x; a.y += v.y;
  }
  float isf = flag[0];
  float di = dinv[node];
  float v0 = a.x*di + ldf(b4, 0, isf);
  float v1 = a.y*di + ldf(b4, 1, isf);
  if (isf > 0.5f){
    ((float*)out)[(size_t)2*node]   = v0;
    ((float*)out)[(size_t)2*node+1] = v1;
  } else {
    ((unsigned short*)out)[(size_t)2*node]   = f2bf(v0);
    ((unsigned short*)out)[(size_t)2*node+1] = f2bf(v1);
  }
}

extern "C" void kernel_launch(void* const* d_in, const int* in_sizes, int n_in,
                              void* d_out, int out_size, void* d_ws, size_t ws_size,
                              hipStream_t stream)
{
  const int B = 256;
  unsigned short* outh = (unsigned short*)d_out;

  if (n_in < 16){
    k_fill<<<(out_size+B-1)/B, B, 0, stream>>>(outh, 0x3F40u, out_size); return;
  }
  const int N = in_sizes[0] / 32;
  const long long E = in_sizes[1] / 2;
  if (in_sizes[0] % 32 != 0 || out_size != 2*N){
    k_fill<<<(out_size+B-1)/B, B, 0, stream>>>(outh, 0x3F60u, out_size); return;
  }
  const bool u16 = (N < 65536);

  // ---- workspace layout ----
  size_t Npad = ((size_t)N + 3) & ~(size_t)3;
  float* ws   = (float*)d_ws;
  float* dinv = ws;                               // Npad
  float* hs2  = dinv + Npad;                      // 2N
  float* flag = hs2 + (size_t)2*N;                // 4
  float* stAll= flag + 4;                         // 4608 stats + gctr + pad + bhist(64) + bcur(64)
  int* bhist  = (int*)(stAll + 4612);             // 64
  int* bcur   = (int*)(stAll + 4676);             // 64
  float* W4f  = stAll + 4740;                     // 192
  unsigned short* Wt1b = (unsigned short*)(W4f + 192);
  unsigned short* Wt2b = Wt1b + 3072;
  unsigned short* Wt3b = Wt2b + 9216;
  int* cnt    = (int*)(Wt3b + 9216);              // N
  int* cursor = cnt + N;                          // N
  int* rowst  = cursor + N;                       // N
  int* perm   = rowst + N;                        // N
  uintptr_t cs_ = (uintptr_t)(perm + N);
  cs_ = (cs_ + 15) & ~(uintptr_t)15;              // 16B-align csr for vector idx loads
  void* csrv  = (void*)cs_;                       // E + 8N entries (padded alloc)
  size_t csrCap = (size_t)E + 8*(size_t)N;
  size_t csrBytes = csrCap * (u16 ? 2 : 4);
  uintptr_t hp_ = cs_ + csrBytes;
  hp_ = (hp_ + 15) & ~(uintptr_t)15;
  unsigned short* HS = (unsigned short*)hp_;      // 96*(N+1) bf16 (row N = zeros; also hosts XS = 32*(N+1))
  unsigned short* Zb = HS + (size_t)96*(N+1);     // 96N bf16
  uintptr_t ec_ = (uintptr_t)(Zb + (size_t)96*N);
  ec_ = (ec_ + 15) & ~(uintptr_t)15;
  void* ecv = (void*)ec_;                         // u16: E+4 uints packed; else 2E ints

  size_t ecBytes = u16 ? ((size_t)E + 4)*4 : ((size_t)2*E + 4)*4;
  size_t needB = (ec_ + ecBytes - (uintptr_t)d_ws) + 64;
  if (ws_size < needB){
    k_fill<<<(out_size+B-1)/B, B, 0, stream>>>(outh, 0x3F00u, out_size); return;
  }

  unsigned short* XS = HS;                        // 32*(N+1) bf16, reuses HS region

  const void* x  = d_in[0];
  const int*  ei = (const int*)d_in[1];
  const void* W1 = d_in[2];
  const void* g1 = d_in[4];  const void* be1 = d_in[5];
  const void* W2 = d_in[6];
  const void* g2 = d_in[8];  const void* be2 = d_in[9];
  const void* W3 = d_in[10];
  const void* g3 = d_in[12]; const void* be3 = d_in[13];
  const void* W4 = d_in[14];
  const void* b4 = d_in[15];

  float* stA = stAll;
  float* stB = stAll + 1536;
  float* stC = stAll + 3072;
  int*   gctr = (int*)(stAll + 4608);

  int gN  = (N + B - 1)/B;
  long long hE = (E + 1)/2;
  int gE2 = (int)((hE + B - 1)/B); if (gE2 < 1) gE2 = 1;
  int nb  = (N + 255)/256;
  int gA  = (N + 15)/16;
  int gL  = (N + 63)/64;
  int gXS = (4*(N+1) + 255)/256;
  int gPS = (N + 255)/256;
  int gF8 = (int)((E + FS_CHUNK - 1)/FS_CHUNK) * 8;
  float invN = 1.0f / (float)N;
  dim3 ablk(12,16);

  // 1) detect + weights + zero cnt/st/gctr/bhist + zero HS row N
  k_prep<<<33, B, 0, stream>>>((const unsigned short*)x, (const unsigned int*)ei,
                               flag, in_sizes[0], E, W1, W2, W3, W4,
                               Wt1b, Wt2b, Wt3b, W4f, cnt, stAll, HS, N);

  if (u16){
    unsigned short* csr = (unsigned short*)csrv;
    unsigned int* ec = (unsigned int*)ecv;
    // 2) degree count + PACKED edge compaction (4B/edge)
    k_cnt2p<<<gE2, B, 0, stream>>>(ei, flag, cnt, ec, E, N);
    // 3) rounded row allocation + degree histogram
    k_emit2<unsigned short><<<nb, B, 0, stream>>>(cnt, gctr, rowst, cursor, dinv, csr, bhist, N);
    // 3b) bucket prefix
    k_bpre<<<1, 64, 0, stream>>>(bhist, bcur);
    // 4) CSR fill + XS build + degree-sorted perm scatter (merged)
    k_fxp<<<gF8 + gXS + gPS, B, 0, stream>>>(ec, cursor, csr, E, N, gF8, gXS,
                                             x, flag, dinv, XS, cnt, bcur, perm);
    // 5) layer 1: degree-sorted 32-col gather + MFMA W1 + stats
    k_aggx<unsigned short><<<gL, B, 0, stream>>>((const uint4*)XS, rowst, cnt, csr, perm, dinv, Wt1b, Zb, stA, N);
    // 6..9) layers 2..3
    k_linm<<<gL, B, 0, stream>>>(Zb, Wt2b, stA, g1, be1, flag, dinv, HS, N, invN);
    k_agg<unsigned short><<<gA, ablk, 0, stream>>>((const uint4*)HS, rowst, cnt, csr, perm, dinv, (uint4*)Zb, stB, N);
    k_linm<<<gL, B, 0, stream>>>(Zb, Wt3b, stB, g2, be2, flag, dinv, HS, N, invN);
    k_agg<unsigned short><<<gA, ablk, 0, stream>>>((const uint4*)HS, rowst, cnt, csr, perm, dinv, (uint4*)Zb, stC, N);
    // 10..11) layer 4 + output
    k_lin4<<<gN, B, 0, stream>>>(Zb, W4f, stC, g3, be3, flag, dinv, hs2, N, invN);
    k_agg2<unsigned short><<<gN, B, 0, stream>>>((const float2*)hs2, rowst, cnt, csr, dinv, b4, flag, d_out, N);
  } else {
    int* csr = (int*)csrv;
    int* ec = (int*)ecv;
    k_cnt2<<<gE2, B, 0, stream>>>(ei, flag, cnt, ec, E, N);
    k_emit2<int><<<nb, B, 0, stream>>>(cnt, gctr, rowst, cursor, dinv, csr, bhist, N);
    k_bpre<<<1, 64, 0, stream>>>(bhist, bcur);
    k_fx<<<gF8 + gXS + gPS, B, 0, stream>>>(ec, cursor, csr, E, N, gF8, gXS,
                                            x, flag, dinv, XS, cnt, bcur, perm);
    k_aggx<int><<<gL, B, 0, stream>>>((const uint4*)XS, rowst, cnt, csr, perm, dinv, Wt1b, Zb, stA, N);
    k_linm<<<gL, B, 0, stream>>>(Zb, Wt2b, stA, g1, be1, flag, dinv, HS, N, invN);
    k_agg<int><<<gA, ablk, 0, stream>>>((const uint4*)HS, rowst, cnt, csr, perm, dinv, (uint4*)Zb, stB, N);
    k_linm<<<gL, B, 0, stream>>>(Zb, Wt3b, stB, g2, be2, flag, dinv, HS, N, invN);
    k_agg<int><<<gA, ablk, 0, stream>>>((const uint4*)HS, rowst, cnt, csr, perm, dinv, (uint4*)Zb, stC, N);
    k_lin4<<<gN, B, 0, stream>>>(Zb, W4f, stC, g3, be3, flag, dinv, hs2, N, invN);
    k_agg2<int><<<gN, B, 0, stream>>>((const float2*)hs2, rowst, cnt, csr, dinv, b4, flag, d_out, N);
  }
}

// Round 9
// 379.821 us; speedup vs baseline: 2.8196x; 2.8196x over previous
//
#include <hip/hip_runtime.h>
#include <hip/hip_bf16.h>

using bf16x8 = __attribute__((ext_vector_type(8))) short;
using f32x4  = __attribute__((ext_vector_type(4))) float;

#define FS_CHUNK 4096

// ---------- helpers ----------
__device__ __forceinline__ float ldf(const void* p, size_t i, float isf){
  if (isf > 0.5f) return ((const float*)p)[i];
  unsigned int u = ((unsigned int)((const unsigned short*)p)[i]) << 16;
  return __uint_as_float(u);
}
__device__ __forceinline__ unsigned short f2bf(float v){
  unsigned int u = __float_as_uint(v);
  u = (u + 0x7FFFu + ((u >> 16) & 1u)) >> 16;   // RNE
  return (unsigned short)u;
}
__device__ __forceinline__ unsigned int pk2(float a, float b){
  return (unsigned int)f2bf(a) | ((unsigned int)f2bf(b) << 16);
}
__device__ __forceinline__ float lo16(unsigned int u){ return __uint_as_float(u << 16); }
__device__ __forceinline__ float hi16(unsigned int u){ return __uint_as_float(u & 0xFFFF0000u); }

// load 8 CSR indices with one (u16) or two (int) vector loads; p must be 16B-aligned
template<typename IT>
__device__ __forceinline__ void load8idx(const IT* p, int* o){
  if (sizeof(IT) == 2){
    uint4 v = *(const uint4*)p;
    o[0] = (int)(v.x & 0xFFFFu); o[1] = (int)(v.x >> 16);
    o[2] = (int)(v.y & 0xFFFFu); o[3] = (int)(v.y >> 16);
    o[4] = (int)(v.z & 0xFFFFu); o[5] = (int)(v.z >> 16);
    o[6] = (int)(v.w & 0xFFFFu); o[7] = (int)(v.w >> 16);
  } else {
    int4 a = ((const int4*)p)[0];
    int4 c = ((const int4*)p)[1];
    o[0]=a.x; o[1]=a.y; o[2]=a.z; o[3]=a.w;
    o[4]=c.x; o[5]=c.y; o[6]=c.z; o[7]=c.w;
  }
}

// wave-aggregated histogram add: one atomic per distinct bucket per wave (G12)
__device__ __forceinline__ void wave_hist_add(int bk, int lane, int* hist){
  unsigned long long todo = __ballot(bk >= 0);
  while (todo){
    int leader = (int)__ffsll((unsigned long long)todo) - 1;
    int bkL = __shfl(bk, leader, 64);
    unsigned long long same = __ballot(bk == bkL) & todo;
    if (lane == leader) atomicAdd(&hist[bkL], (int)__popcll(same));
    todo &= ~same;
  }
}

// wave-aggregated scatter position: one atomic per distinct bucket per wave; returns pos (or -1)
__device__ __forceinline__ int wave_scatter_pos(int bk, int lane, int* cur){
  int pos = -1;
  unsigned long long todo = __ballot(bk >= 0);
  while (todo){
    int leader = (int)__ffsll((unsigned long long)todo) - 1;
    int bkL = __shfl(bk, leader, 64);
    unsigned long long same = __ballot(bk == bkL) & todo;
    int base = 0;
    if (lane == leader) base = atomicAdd(&cur[bkL], (int)__popcll(same));
    base = __shfl(base, leader, 64);
    if ((same >> lane) & 1ULL)
      pos = base + (int)__popcll(same & ((1ULL << lane) - 1ULL));
    todo &= ~same;
  }
  return pos;
}

__global__ void k_fill(unsigned short* o, unsigned short v, int n){
  int i = blockIdx.x*blockDim.x + threadIdx.x;
  if (i < n) o[i] = v;
}

// ---------- fused: dtype detect + weight convert (block 0) + zero cnt/st/gctr/bhist/HSrowN ----------
__global__ void k_prep(const unsigned short* xh, const unsigned int* eu,
                       float* flag, int nelemX, long long E,
                       const void* W1, const void* W2, const void* W3, const void* W4,
                       unsigned short* __restrict__ Wt1, unsigned short* __restrict__ Wt2,
                       unsigned short* __restrict__ Wt3, float* __restrict__ W4f,
                       int* __restrict__ cnt, float* __restrict__ stAll,
                       unsigned short* __restrict__ HS, int n){
  int t = threadIdx.x;
  if (blockIdx.x > 0){
    if (blockIdx.x == 1 && t < 96) HS[(size_t)96*n + t] = 0;   // zero row n (dummy gather target)
    int total = n + 4676;                 // cnt[N] + stats/gctr/pad + bhist(64)
    for (int i = (int)(blockIdx.x-1)*256 + t; i < total; i += (int)(gridDim.x-1)*256){
      if (i < n) cnt[i] = 0; else stAll[i - n] = 0.f;   // 0.0f bits == int 0
    }
    return;
  }
  __shared__ int sf32, si64;
  __shared__ float sisf;
  if (t == 0){ sf32 = 0; si64 = 1; }
  __syncthreads();
  {
    int i = 2*t;
    if (i < nelemX){
      unsigned e8 = (xh[i] >> 7) & 0xFFu;
      if (e8 >= 140u) sf32 = 1;
    }
    if ((long long)(2*t + 1) < 2*E){
      if (eu[2*t + 1] != 0u) si64 = 0;
    }
  }
  __syncthreads();
  if (t == 0){
    flag[0] = (float)sf32; flag[1] = (float)si64;
    sisf = (float)sf32;
  }
  __syncthreads();
  float isf = sisf;
  for (int q = t; q < 3072; q += 256){
    int nn = q >> 5, k = q & 31;
    Wt1[q] = f2bf(ldf(W1, (size_t)96*k + nn, isf));
  }
  for (int q = t; q < 9216; q += 256){
    int nn = q/96, k = q - 96*nn;
    Wt2[q] = f2bf(ldf(W2, (size_t)96*k + nn, isf));
    Wt3[q] = f2bf(ldf(W3, (size_t)96*k + nn, isf));
  }
  if (t < 192) W4f[t] = ldf(W4, t, isf);
}

// ---------- degree count + edge compaction, u16-PACKED (dst<<16 | src), 4B/edge ----------
__global__ void k_cnt2p(const int* __restrict__ ei, const float* __restrict__ flag,
                        int* __restrict__ cnt, unsigned int* __restrict__ ec,
                        long long E, int n){
  long long i = (long long)blockIdx.x*blockDim.x + threadIdx.x;  // handles edges 2i, 2i+1
  long long i0 = 2*i;
  if (i0 >= E) return;
  bool i64 = (flag[1] > 0.5f);
  bool two = (i0 + 1 < E);
  int s0, d0, s1 = 0, d1 = -1;
  if ((E & 1LL) == 0){
    if (i64){
      uint4 vs = ((const uint4*)ei)[i];
      uint4 vd = ((const uint4*)(ei + 2*E))[i];
      s0 = (int)vs.x; s1 = (int)vs.z; d0 = (int)vd.x; d1 = (int)vd.z;
    } else {
      int2 vs = ((const int2*)ei)[i];
      int2 vd = ((const int2*)(ei + E))[i];
      s0 = vs.x; s1 = vs.y; d0 = vd.x; d1 = vd.y;
    }
  } else {
    if (i64){ s0 = ei[2*i0]; d0 = ei[2*E + 2*i0];
              if (two){ s1 = ei[2*i0+2]; d1 = ei[2*E + 2*i0 + 2]; } }
    else    { s0 = ei[i0];   d0 = ei[E + i0];
              if (two){ s1 = ei[i0+1];   d1 = ei[E + i0 + 1]; } }
  }
  bool ok0 = ((unsigned)s0 < (unsigned)n) && ((unsigned)d0 < (unsigned)n);
  bool ok1 = two && ((unsigned)s1 < (unsigned)n) && ((unsigned)d1 < (unsigned)n);
  unsigned p0 = ok0 ? (((unsigned)d0 << 16) | (unsigned)s0) : 0xFFFFFFFFu;
  unsigned p1 = ok1 ? (((unsigned)d1 << 16) | (unsigned)s1) : 0xFFFFFFFFu;
  if (two){
    uint2 o; o.x = p0; o.y = p1;
    ((uint2*)ec)[i] = o;
  } else {
    ec[i0] = p0;
  }
  if (ok0) atomicAdd(&cnt[d0], 1);
  if (ok1) atomicAdd(&cnt[d1], 1);
}

// ---------- degree count + edge compaction, int pairs (big-N path) ----------
__global__ void k_cnt2(const int* __restrict__ ei, const float* __restrict__ flag,
                       int* __restrict__ cnt, int* __restrict__ ec,
                       long long E, int n){
  long long i = (long long)blockIdx.x*blockDim.x + threadIdx.x;
  long long i0 = 2*i;
  if (i0 >= E) return;
  bool i64 = (flag[1] > 0.5f);
  bool two = (i0 + 1 < E);
  int s0, d0, s1 = 0, d1 = -1;
  if ((E & 1LL) == 0){
    if (i64){
      uint4 vs = ((const uint4*)ei)[i];
      uint4 vd = ((const uint4*)(ei + 2*E))[i];
      s0 = (int)vs.x; s1 = (int)vs.z; d0 = (int)vd.x; d1 = (int)vd.z;
    } else {
      int2 vs = ((const int2*)ei)[i];
      int2 vd = ((const int2*)(ei + E))[i];
      s0 = vs.x; s1 = vs.y; d0 = vd.x; d1 = vd.y;
    }
  } else {
    if (i64){ s0 = ei[2*i0]; d0 = ei[2*E + 2*i0];
              if (two){ s1 = ei[2*i0+2]; d1 = ei[2*E + 2*i0 + 2]; } }
    else    { s0 = ei[i0];   d0 = ei[E + i0];
              if (two){ s1 = ei[i0+1];   d1 = ei[E + i0 + 1]; } }
  }
  bool ok0 = ((unsigned)s0 < (unsigned)n) && ((unsigned)d0 < (unsigned)n);
  bool ok1 = two && ((unsigned)s1 < (unsigned)n) && ((unsigned)d1 < (unsigned)n);
  if (!ok0){ s0 = -1; d0 = -1; }
  if (!ok1){ s1 = -1; d1 = -1; }
  if (two){
    int4 o; o.x = s0; o.y = d0; o.z = s1; o.w = d1;
    ((int4*)ec)[i] = o;
  } else {
    int2 o; o.x = s0; o.y = d0;
    ((int2*)ec)[i0] = o;
  }
  if (ok0) atomicAdd(&cnt[d0], 1);
  if (ok1) atomicAdd(&cnt[d1], 1);
}

// ---------- row allocation (deg rounded to mult of 8) + degree-bucket histogram (wave-agg) ----------
template<typename IT>
__global__ void k_emit2(const int* __restrict__ cnt, int* __restrict__ gctr,
                        int* __restrict__ rowst, int* __restrict__ cursor,
                        float* __restrict__ dinv, IT* __restrict__ csr,
                        int* __restrict__ bhist, int n){
  int i = blockIdx.x*256 + threadIdx.x;
  int lane = threadIdx.x & 63;
  int v  = (i < n) ? cnt[i] : 0;
  int rv = (v + 7) & ~7;                  // rounded allocation
  int s = rv;
  #pragma unroll
  for (int off = 1; off < 64; off <<= 1){
    int u = __shfl_up(s, off, 64);
    if (lane >= off) s += u;
  }
  int wtot = __shfl(s, 63, 64);
  int base = 0;
  if (lane == 63) base = atomicAdd(gctr, wtot);
  base = __shfl(base, 63, 64);
  if (i < n){
    int r = base + s - rv;
    rowst[i]  = r;
    cursor[i] = r;
    dinv[i]   = rsqrtf((float)(1 + v));
    for (int p = r + v; p < r + rv; ++p) csr[p] = (IT)n;   // dummy -> zero row
  }
  int bk = (i < n) ? ((rv >> 3) > 63 ? 63 : (rv >> 3)) : -1;
  wave_hist_add(bk, lane, bhist);
}

// ---------- bucket prefix: 64 buckets, one wave ----------
__global__ void k_bpre(const int* __restrict__ bhist, int* __restrict__ bcur){
  int t = threadIdx.x;                    // 64 threads, one wave
  int h = bhist[t];
  int s = h;
  #pragma unroll
  for (int off = 1; off < 64; off <<= 1){
    int u = __shfl_up(s, off, 64);
    if (t >= off) s += u;
  }
  bcur[t] = s - h;                        // exclusive base; serves as scatter cursor
}

// ---------- merged: CSR slot fill (packed ec) + XS build + degree-sorted perm scatter ----------
__global__ __launch_bounds__(256) void k_fxp(const unsigned int* __restrict__ ec,
      int* __restrict__ cursor, unsigned short* __restrict__ csr,
      long long E, int n, int gF8, int gXS,
      const void* __restrict__ x, const float* __restrict__ flag,
      const float* __restrict__ dinv, unsigned short* __restrict__ XS,
      const int* __restrict__ cnt, int* __restrict__ bcur, int* __restrict__ perm){
  int t = threadIdx.x;
  if ((int)blockIdx.x < gF8){
    int part = blockIdx.x & 7;
    long long base = (long long)(blockIdx.x >> 3) * FS_CHUNK;
    int pl = (int)(((long long)n *  part     ) >> 3);
    int pr = (int)(((long long)n * (part + 1)) >> 3);
    long long lim = base + FS_CHUNK < E ? base + FS_CHUNK : E;
    for (long long i = base + 4*t; i < lim; i += 1024){
      uint4 v = ((const uint4*)ec)[i >> 2];          // edges i..i+3 packed (dst<<16|src)
      { int d = (int)(v.x >> 16);
        if (d >= pl && d < pr){ int p = atomicAdd(&cursor[d], 1); csr[p] = (unsigned short)(v.x & 0xFFFFu); } }
      if (i + 1 < lim){ int d = (int)(v.y >> 16);
        if (d >= pl && d < pr){ int p = atomicAdd(&cursor[d], 1); csr[p] = (unsigned short)(v.y & 0xFFFFu); } }
      if (i + 2 < lim){ int d = (int)(v.z >> 16);
        if (d >= pl && d < pr){ int p = atomicAdd(&cursor[d], 1); csr[p] = (unsigned short)(v.z & 0xFFFFu); } }
      if (i + 3 < lim){ int d = (int)(v.w >> 16);
        if (d >= pl && d < pr){ int p = atomicAdd(&cursor[d], 1); csr[p] = (unsigned short)(v.w & 0xFFFFu); } }
    }
    return;
  }
  if ((int)blockIdx.x < gF8 + gXS){
    int q = (int)(blockIdx.x - gF8)*256 + t;
    if (q < 4*(n+1)){
      int node = q >> 2, part = q & 3;
      uint4 o;
      if (node < n){
        float isf = flag[0];
        float di = dinv[node];
        if (isf > 0.5f){
          const float* xr = (const float*)x + (size_t)32*node + 8*part;
          o.x = pk2(xr[0]*di, xr[1]*di); o.y = pk2(xr[2]*di, xr[3]*di);
          o.z = pk2(xr[4]*di, xr[5]*di); o.w = pk2(xr[6]*di, xr[7]*di);
        } else {
          uint4 v = ((const uint4*)x)[(size_t)4*node + part];
          o.x = pk2(lo16(v.x)*di, hi16(v.x)*di);
          o.y = pk2(lo16(v.y)*di, hi16(v.y)*di);
          o.z = pk2(lo16(v.z)*di, hi16(v.z)*di);
          o.w = pk2(lo16(v.w)*di, hi16(v.w)*di);
        }
      } else { o.x = o.y = o.z = o.w = 0u; }        // zero row n (dummy gather target)
      ((uint4*)XS)[q] = o;
    }
    return;
  }
  // perm scatter: degree-bucket sort of node ids (wave-aggregated atomics)
  int i = (int)(blockIdx.x - gF8 - gXS)*256 + t;
  int bk = -1;
  if (i < n){
    int rv = (cnt[i] + 7) & ~7;
    bk = rv >> 3; if (bk > 63) bk = 63;
  }
  int pos = wave_scatter_pos(bk, t & 63, bcur);
  if (i < n) perm[pos] = i;
}

// ---------- merged fill + XS + perm, int path (big N) ----------
__global__ __launch_bounds__(256) void k_fx(const int* __restrict__ ec,
      int* __restrict__ cursor, int* __restrict__ csr,
      long long E, int n, int gF8, int gXS,
      const void* __restrict__ x, const float* __restrict__ flag,
      const float* __restrict__ dinv, unsigned short* __restrict__ XS,
      const int* __restrict__ cnt, int* __restrict__ bcur, int* __restrict__ perm){
  int t = threadIdx.x;
  if ((int)blockIdx.x < gF8){
    int part = blockIdx.x & 7;
    long long base = (long long)(blockIdx.x >> 3) * FS_CHUNK;
    int pl = (int)(((long long)n *  part     ) >> 3);
    int pr = (int)(((long long)n * (part + 1)) >> 3);
    long long lim = base + FS_CHUNK < E ? base + FS_CHUNK : E;
    for (long long i = base + 2*t; i < lim; i += 512){
      int4 v = ((const int4*)ec)[i >> 1];
      if (v.y >= pl && v.y < pr && (unsigned)v.x < (unsigned)n){
        int p = atomicAdd(&cursor[v.y], 1);
        csr[p] = v.x;
      }
      if (i + 1 < lim && v.w >= pl && v.w < pr && (unsigned)v.z < (unsigned)n){
        int p = atomicAdd(&cursor[v.w], 1);
        csr[p] = v.z;
      }
    }
    return;
  }
  if ((int)blockIdx.x < gF8 + gXS){
    int q = (int)(blockIdx.x - gF8)*256 + t;
    if (q < 4*(n+1)){
      int node = q >> 2, part = q & 3;
      uint4 o;
      if (node < n){
        float isf = flag[0];
        float di = dinv[node];
        if (isf > 0.5f){
          const float* xr = (const float*)x + (size_t)32*node + 8*part;
          o.x = pk2(xr[0]*di, xr[1]*di); o.y = pk2(xr[2]*di, xr[3]*di);
          o.z = pk2(xr[4]*di, xr[5]*di); o.w = pk2(xr[6]*di, xr[7]*di);
        } else {
          uint4 v = ((const uint4*)x)[(size_t)4*node + part];
          o.x = pk2(lo16(v.x)*di, hi16(v.x)*di);
          o.y = pk2(lo16(v.y)*di, hi16(v.y)*di);
          o.z = pk2(lo16(v.z)*di, hi16(v.z)*di);
          o.w = pk2(lo16(v.w)*di, hi16(v.w)*di);
        }
      } else { o.x = o.y = o.z = o.w = 0u; }
      ((uint4*)XS)[q] = o;
    }
    return;
  }
  int i = (int)(blockIdx.x - gF8 - gXS)*256 + t;
  int bk = -1;
  if (i < n){
    int rv = (cnt[i] + 7) & ~7;
    bk = rv >> 3; if (bk > 63) bk = 63;
  }
  int pos = wave_scatter_pos(bk, t & 63, bcur);
  if (i < n) perm[pos] = i;
}

#define ACC8(v) { a0+=lo16((v).x); a1+=hi16((v).x); a2+=lo16((v).y); a3+=hi16((v).y); \
                  a4+=lo16((v).z); a5+=hi16((v).z); a6+=lo16((v).w); a7+=hi16((v).w); }

// ---------- layer 1: degree-sorted gather-sum XS + dinv + MFMA W1 + stats ----------
template<typename IT>
__global__ __launch_bounds__(256) void k_aggx(const uint4* __restrict__ xs4,
      const int* __restrict__ rowst, const int* __restrict__ cnt,
      const IT* __restrict__ csr, const int* __restrict__ perm,
      const float* __restrict__ dinv,
      const unsigned short* __restrict__ Wt1b,
      unsigned short* __restrict__ Zb, float* __restrict__ stout, int n){
  __shared__ __align__(16) unsigned short Xs[64][40];
  __shared__ __align__(16) unsigned short Wt[96][40];
  __shared__ float bs[96], bq[96];
  int t = threadIdx.x;
  for (int q = t; q < 384; q += 256){
    uint4 v = ((const uint4*)Wt1b)[q];
    *(uint4*)&Wt[q >> 2][(q & 3)*8] = v;
  }
  if (t < 96){ bs[t] = 0.f; bq[t] = 0.f; }
  int g = t & 3, ty = t >> 2;
  int idx = blockIdx.x*64 + ty;
  int node = (idx < n) ? perm[idx] : -1;
  float a0=0.f,a1=0.f,a2=0.f,a3=0.f,a4=0.f,a5=0.f,a6=0.f,a7=0.f;
  if (node >= 0){
    uint4 v = xs4[(size_t)node*4 + g];           // self-loop contribution
    ACC8(v);
    int bq_ = rowst[node];
    int bnd = bq_ + ((cnt[node] + 7) & ~7);      // padded, uniform batches of 8
    for (int j = bq_; j < bnd; j += 8){
      int ix[8];
      load8idx<IT>(csr + j, ix);
      uint4 v0 = xs4[(size_t)ix[0]*4 + g];
      uint4 v1 = xs4[(size_t)ix[1]*4 + g];
      uint4 v2 = xs4[(size_t)ix[2]*4 + g];
      uint4 v3 = xs4[(size_t)ix[3]*4 + g];
      uint4 v4 = xs4[(size_t)ix[4]*4 + g];
      uint4 v5 = xs4[(size_t)ix[5]*4 + g];
      uint4 v6 = xs4[(size_t)ix[6]*4 + g];
      uint4 v7 = xs4[(size_t)ix[7]*4 + g];
      ACC8(v0); ACC8(v1); ACC8(v2); ACC8(v3);
      ACC8(v4); ACC8(v5); ACC8(v6); ACC8(v7);
    }
    float di = dinv[node];
    a0*=di; a1*=di; a2*=di; a3*=di; a4*=di; a5*=di; a6*=di; a7*=di;
  }
  uint4 o;
  o.x = pk2(a0,a1); o.y = pk2(a2,a3); o.z = pk2(a4,a5); o.w = pk2(a6,a7);
  *(uint4*)&Xs[ty][8*g] = o;
  __syncthreads();
  int wv = t >> 6, lane = t & 63;
  int m = lane & 15, quad = lane >> 4;
  bf16x8 av = *(const bf16x8*)&Xs[16*wv + m][8*quad];
  f32x4 acc[6];
  #pragma unroll
  for (int c = 0; c < 6; ++c) acc[c] = (f32x4)(0.f);
  #pragma unroll
  for (int c = 0; c < 6; ++c){
    bf16x8 bv = *(const bf16x8*)&Wt[16*c + m][8*quad];
    acc[c] = __builtin_amdgcn_mfma_f32_16x16x32_bf16(av, bv, acc[c], 0, 0, 0);
  }
  int rowbase = blockIdx.x*64 + 16*wv + 4*quad;
  int nw[4];
  #pragma unroll
  for (int r = 0; r < 4; ++r){ int ii = rowbase + r; nw[r] = (ii < n) ? perm[ii] : -1; }
  #pragma unroll
  for (int c = 0; c < 6; ++c){
    int col = 16*c + m;
    float s = 0.f, q = 0.f;
    #pragma unroll
    for (int r = 0; r < 4; ++r){
      if (nw[r] >= 0){
        unsigned short h = f2bf(acc[c][r]);
        Zb[(size_t)96*nw[r] + col] = h;
        float br = __uint_as_float(((unsigned int)h) << 16);
        s += br; q += br*br;
      }
    }
    atomicAdd(&bs[col], s);
    atomicAdd(&bq[col], q);
  }
  __syncthreads();
  if (t < 96){
    int rep = blockIdx.x & 7;
    atomicAdd(&stout[192*rep + t],      bs[t]);
    atomicAdd(&stout[192*rep + 96 + t], bq[t]);
  }
}

// ---------- degree-sorted CSR gather aggregation (96 cols) + fused BN stats ----------
template<typename IT>
__global__ __launch_bounds__(192) void k_agg(const uint4* __restrict__ hsr,
      const int* __restrict__ rowst, const int* __restrict__ cnt,
      const IT* __restrict__ csr, const int* __restrict__ perm,
      const float* __restrict__ dinv, uint4* __restrict__ zb4,
      float* __restrict__ stout, int n){
  __shared__ float ls[16][97], lq[16][97];
  int g = threadIdx.x, ty = threadIdx.y;
  int t = ty*12 + g;
  int idx = blockIdx.x*16 + ty;
  int node = (idx < n) ? perm[idx] : -1;
  float r[8];
  if (node >= 0){
    uint4 v = hsr[(size_t)node*12 + g];
    float a0 = lo16(v.x), a1 = hi16(v.x), a2 = lo16(v.y), a3 = hi16(v.y);
    float a4 = lo16(v.z), a5 = hi16(v.z), a6 = lo16(v.w), a7 = hi16(v.w);
    int bq_ = rowst[node];
    int bnd = bq_ + ((cnt[node] + 7) & ~7);      // padded, uniform batches of 8
    for (int j = bq_; j < bnd; j += 8){
      int ix[8];
      load8idx<IT>(csr + j, ix);
      uint4 v0 = hsr[(size_t)ix[0]*12 + g];
      uint4 v1 = hsr[(size_t)ix[1]*12 + g];
      uint4 v2 = hsr[(size_t)ix[2]*12 + g];
      uint4 v3 = hsr[(size_t)ix[3]*12 + g];
      uint4 v4 = hsr[(size_t)ix[4]*12 + g];
      uint4 v5 = hsr[(size_t)ix[5]*12 + g];
      uint4 v6 = hsr[(size_t)ix[6]*12 + g];
      uint4 v7 = hsr[(size_t)ix[7]*12 + g];
      ACC8(v0); ACC8(v1); ACC8(v2); ACC8(v3);
      ACC8(v4); ACC8(v5); ACC8(v6); ACC8(v7);
    }
    float di = dinv[node];
    uint4 o;
    o.x = pk2(a0*di, a1*di);
    o.y = pk2(a2*di, a3*di);
    o.z = pk2(a4*di, a5*di);
    o.w = pk2(a6*di, a7*di);
    zb4[(size_t)node*12 + g] = o;
    r[0]=lo16(o.x); r[1]=hi16(o.x); r[2]=lo16(o.y); r[3]=hi16(o.y);
    r[4]=lo16(o.z); r[5]=hi16(o.z); r[6]=lo16(o.w); r[7]=hi16(o.w);
  } else {
    #pragma unroll
    for (int jj = 0; jj < 8; ++jj) r[jj] = 0.f;
  }
  #pragma unroll
  for (int jj = 0; jj < 8; ++jj){
    ls[ty][8*g + jj] = r[jj];
    lq[ty][8*g + jj] = r[jj]*r[jj];
  }
  __syncthreads();
  if (t < 96){
    float s = 0.f, q = 0.f;
    #pragma unroll
    for (int rr = 0; rr < 16; ++rr){ s += ls[rr][t]; q += lq[rr][t]; }
    int rep = blockIdx.x & 7;
    atomicAdd(&stout[192*rep + t],      s);
    atomicAdd(&stout[192*rep + 96 + t], q);
  }
}

// ---------- MFMA mid layer ----------
__global__ __launch_bounds__(256) void k_linm(const unsigned short* __restrict__ zb,
      const unsigned short* __restrict__ Wtb, const float* __restrict__ st,
      const void* __restrict__ gam, const void* __restrict__ bet,
      const float* __restrict__ flag, const float* __restrict__ dinv,
      unsigned short* __restrict__ HS, int n, float invN){
  __shared__ float sa[96], sc[96];
  __shared__ __align__(16) unsigned short Ys[64][104];
  __shared__ __align__(16) unsigned short Wt[96][104];
  int t = threadIdx.x;
  if (t < 96){
    float ssum = 0.f, qsum = 0.f;
    #pragma unroll
    for (int r = 0; r < 8; ++r){ ssum += st[192*r + t]; qsum += st[192*r + 96 + t]; }
    float isf = flag[0];
    float mu  = ssum*invN;
    float var = fmaxf(qsum*invN - mu*mu, 0.f);
    float istd = rsqrtf(var + 1e-5f);
    float a = ldf(gam, t, isf)*istd;
    sa[t] = a; sc[t] = ldf(bet, t, isf) - mu*a;
  }
  for (int q = t; q < 1152; q += 256){
    uint4 v = ((const uint4*)Wtb)[q];
    *(uint4*)&Wt[q/12][8*(q - 12*(q/12))] = v;
  }
  __syncthreads();
  {
    int row = t >> 2, part = t & 3;
    int node = blockIdx.x*64 + row;
    if (node < n){
      const uint4* zr = (const uint4*)(zb + (size_t)96*node) + 3*part;
      #pragma unroll
      for (int q = 0; q < 3; ++q){
        uint4 zz = zr[q];
        int k = 24*part + 8*q;
        float y0 = fmaxf(lo16(zz.x)*sa[k]   + sc[k],   0.f);
        float y1 = fmaxf(hi16(zz.x)*sa[k+1] + sc[k+1], 0.f);
        float y2 = fmaxf(lo16(zz.y)*sa[k+2] + sc[k+2], 0.f);
        float y3 = fmaxf(hi16(zz.y)*sa[k+3] + sc[k+3], 0.f);
        float y4 = fmaxf(lo16(zz.z)*sa[k+4] + sc[k+4], 0.f);
        float y5 = fmaxf(hi16(zz.z)*sa[k+5] + sc[k+5], 0.f);
        float y6 = fmaxf(lo16(zz.w)*sa[k+6] + sc[k+6], 0.f);
        float y7 = fmaxf(hi16(zz.w)*sa[k+7] + sc[k+7], 0.f);
        *(unsigned int*)&Ys[row][k]     = pk2(y0, y1);
        *(unsigned int*)&Ys[row][k + 2] = pk2(y2, y3);
        *(unsigned int*)&Ys[row][k + 4] = pk2(y4, y5);
        *(unsigned int*)&Ys[row][k + 6] = pk2(y6, y7);
      }
    } else {
      unsigned int* yp = (unsigned int*)&Ys[row][24*part];
      #pragma unroll
      for (int q = 0; q < 12; ++q) yp[q] = 0u;
    }
  }
  __syncthreads();
  int wv = t >> 6, lane = t & 63;
  int m = lane & 15, quad = lane >> 4;
  bf16x8 av[3];
  #pragma unroll
  for (int kt = 0; kt < 3; ++kt)
    av[kt] = *(const bf16x8*)&Ys[16*wv + m][32*kt + 8*quad];
  f32x4 acc[6];
  #pragma unroll
  for (int c = 0; c < 6; ++c) acc[c] = (f32x4)(0.f);
  #pragma unroll
  for (int c = 0; c < 6; ++c){
    const unsigned short* wrow = &Wt[16*c + m][8*quad];
    #pragma unroll
    for (int kt = 0; kt < 3; ++kt){
      bf16x8 bv = *(const bf16x8*)(wrow + 32*kt);
      acc[c] = __builtin_amdgcn_mfma_f32_16x16x32_bf16(av[kt], bv, acc[c], 0, 0, 0);
    }
  }
  int rowbase = blockIdx.x*64 + 16*wv + 4*quad;
  float div[4];
  #pragma unroll
  for (int r = 0; r < 4; ++r){ int rr = rowbase + r; div[r] = (rr < n) ? dinv[rr] : 0.f; }
  #pragma unroll
  for (int c = 0; c < 6; ++c){
    int col = 16*c + m;
    #pragma unroll
    for (int r = 0; r < 4; ++r){
      int rr = rowbase + r;
      if (rr < n) HS[(size_t)96*rr + col] = f2bf(acc[c][r]*div[r]);
    }
  }
}

// ---------- layer 4 (96->2, VALU) ----------
__global__ __launch_bounds__(256) void k_lin4(const unsigned short* __restrict__ zb,
      const float* __restrict__ Wf, const float* __restrict__ st,
      const void* __restrict__ gam, const void* __restrict__ bet,
      const float* __restrict__ flag, const float* __restrict__ dinv,
      float* __restrict__ hs2, int n, float invN){
  __shared__ float sa[96], sc[96];
  int t = threadIdx.x;
  if (t < 96){
    float ssum = 0.f, qsum = 0.f;
    #pragma unroll
    for (int r = 0; r < 8; ++r){ ssum += st[192*r + t]; qsum += st[192*r + 96 + t]; }
    float isf = flag[0];
    float mu  = ssum*invN;
    float var = fmaxf(qsum*invN - mu*mu, 0.f);
    float istd = rsqrtf(var + 1e-5f);
    float a = ldf(gam, t, isf)*istd;
    sa[t] = a; sc[t] = ldf(bet, t, isf) - mu*a;
  }
  __syncthreads();
  int i = blockIdx.x*blockDim.x + t;
  if (i >= n) return;
  const uint4* zr = (const uint4*)(zb + (size_t)96*i);
  float a0 = 0.f, a1 = 0.f;
  #pragma unroll
  for (int q = 0; q < 12; ++q){
    uint4 zz = zr[q];
    int k = 8*q;
    float y;
    y = fmaxf(lo16(zz.x)*sa[k]   + sc[k],   0.f); a0 += y*Wf[2*k];    a1 += y*Wf[2*k+1];
    y = fmaxf(hi16(zz.x)*sa[k+1] + sc[k+1], 0.f); a0 += y*Wf[2*k+2];  a1 += y*Wf[2*k+3];
    y = fmaxf(lo16(zz.y)*sa[k+2] + sc[k+2], 0.f); a0 += y*Wf[2*k+4];  a1 += y*Wf[2*k+5];
    y = fmaxf(hi16(zz.y)*sa[k+3] + sc[k+3], 0.f); a0 += y*Wf[2*k+6];  a1 += y*Wf[2*k+7];
    y = fmaxf(lo16(zz.z)*sa[k+4] + sc[k+4], 0.f); a0 += y*Wf[2*k+8];  a1 += y*Wf[2*k+9];
    y = fmaxf(hi16(zz.z)*sa[k+5] + sc[k+5], 0.f); a0 += y*Wf[2*k+10]; a1 += y*Wf[2*k+11];
    y = fmaxf(lo16(zz.w)*sa[k+6] + sc[k+6], 0.f); a0 += y*Wf[2*k+12]; a1 += y*Wf[2*k+13];
    y = fmaxf(hi16(zz.w)*sa[k+7] + sc[k+7], 0.f); a0 += y*Wf[2*k+14]; a1 += y*Wf[2*k+15];
  }
  float di = dinv[i];
  hs2[(size_t)2*i]   = di*a0;
  hs2[(size_t)2*i+1] = di*a1;
}

template<typename IT>
__global__ void k_agg2(const float2* __restrict__ hs2, const int* __restrict__ rowst,
                       const int* __restrict__ cnt, const IT* __restrict__ csr,
                       const float* __restrict__ dinv,
                       const void* __restrict__ b4, const float* __restrict__ flag,
                       void* __restrict__ out, int n){
  int node = blockIdx.x*blockDim.x + threadIdx.x;
  if (node >= n) return;
  float2 a = hs2[node];
  int b = rowst[node], e = b + cnt[node];   // real count only (no padded reads)
  int j = b;
  for (; j + 3 < e; j += 4){
    float2 v0 = hs2[(size_t)csr[j]];
    float2 v1 = hs2[(size_t)csr[j+1]];
    float2 v2 = hs2[(size_t)csr[j+2]];
    float2 v3 = hs2[(size_t)csr[j+3]];
    a.x += v0.x + v1.x + v2.x + v3.x;
    a.y += v0.y + v1.y + v2.y + v3.y;
  }
  for (; j < e; ++j){
    float2 v = hs2[(size_t)csr[j]];
    a.x += v.x; a.y += v.y;
  }
  float isf = flag[0];
  float di = dinv[node];
  float v0 = a.x*di + ldf(b4, 0, isf);
  float v1 = a.y*di + ldf(b4, 1, isf);
  if (isf > 0.5f){
    ((float*)out)[(size_t)2*node]   = v0;
    ((float*)out)[(size_t)2*node+1] = v1;
  } else {
    ((unsigned short*)out)[(size_t)2*node]   = f2bf(v0);
    ((unsigned short*)out)[(size_t)2*node+1] = f2bf(v1);
  }
}

extern "C" void kernel_launch(void* const* d_in, const int* in_sizes, int n_in,
                              void* d_out, int out_size, void* d_ws, size_t ws_size,
                              hipStream_t stream)
{
  const int B = 256;
  unsigned short* outh = (unsigned short*)d_out;

  if (n_in < 16){
    k_fill<<<(out_size+B-1)/B, B, 0, stream>>>(outh, 0x3F40u, out_size); return;
  }
  const int N = in_sizes[0] / 32;
  const long long E = in_sizes[1] / 2;
  if (in_sizes[0] % 32 != 0 || out_size != 2*N){
    k_fill<<<(out_size+B-1)/B, B, 0, stream>>>(outh, 0x3F60u, out_size); return;
  }
  const bool u16 = (N < 65536);

  // ---- workspace layout ----
  size_t Npad = ((size_t)N + 3) & ~(size_t)3;
  float* ws   = (float*)d_ws;
  float* dinv = ws;                               // Npad
  float* hs2  = dinv + Npad;                      // 2N
  float* flag = hs2 + (size_t)2*N;                // 4
  float* stAll= flag + 4;                         // 4608 stats + gctr + pad + bhist(64) + bcur(64)
  int* bhist  = (int*)(stAll + 4612);             // 64
  int* bcur   = (int*)(stAll + 4676);             // 64
  float* W4f  = stAll + 4740;                     // 192
  unsigned short* Wt1b = (unsigned short*)(W4f + 192);
  unsigned short* Wt2b = Wt1b + 3072;
  unsigned short* Wt3b = Wt2b + 9216;
  int* cnt    = (int*)(Wt3b + 9216);              // N
  int* cursor = cnt + N;                          // N
  int* rowst  = cursor + N;                       // N
  int* perm   = rowst + N;                        // N
  uintptr_t cs_ = (uintptr_t)(perm + N);
  cs_ = (cs_ + 15) & ~(uintptr_t)15;              // 16B-align csr for vector idx loads
  void* csrv  = (void*)cs_;                       // E + 8N entries (padded alloc)
  size_t csrCap = (size_t)E + 8*(size_t)N;
  size_t csrBytes = csrCap * (u16 ? 2 : 4);
  uintptr_t hp_ = cs_ + csrBytes;
  hp_ = (hp_ + 15) & ~(uintptr_t)15;
  unsigned short* HS = (unsigned short*)hp_;      // 96*(N+1) bf16 (row N = zeros; also hosts XS = 32*(N+1))
  unsigned short* Zb = HS + (size_t)96*(N+1);     // 96N bf16
  uintptr_t ec_ = (uintptr_t)(Zb + (size_t)96*N);
  ec_ = (ec_ + 15) & ~(uintptr_t)15;
  void* ecv = (void*)ec_;                         // u16: E+4 uints packed; else 2E ints

  size_t ecBytes = u16 ? ((size_t)E + 4)*4 : ((size_t)2*E + 4)*4;
  size_t needB = (ec_ + ecBytes - (uintptr_t)d_ws) + 64;
  if (ws_size < needB){
    k_fill<<<(out_size+B-1)/B, B, 0, stream>>>(outh, 0x3F00u, out_size); return;
  }

  unsigned short* XS = HS;                        // 32*(N+1) bf16, reuses HS region

  const void* x  = d_in[0];
  const int*  ei = (const int*)d_in[1];
  const void* W1 = d_in[2];
  const void* g1 = d_in[4];  const void* be1 = d_in[5];
  const void* W2 = d_in[6];
  const void* g2 = d_in[8];  const void* be2 = d_in[9];
  const void* W3 = d_in[10];
  const void* g3 = d_in[12]; const void* be3 = d_in[13];
  const void* W4 = d_in[14];
  const void* b4 = d_in[15];

  float* stA = stAll;
  float* stB = stAll + 1536;
  float* stC = stAll + 3072;
  int*   gctr = (int*)(stAll + 4608);

  int gN  = (N + B - 1)/B;
  long long hE = (E + 1)/2;
  int gE2 = (int)((hE + B - 1)/B); if (gE2 < 1) gE2 = 1;
  int nb  = (N + 255)/256;
  int gA  = (N + 15)/16;
  int gL  = (N + 63)/64;
  int gXS = (4*(N+1) + 255)/256;
  int gPS = (N + 255)/256;
  int gF8 = (int)((E + FS_CHUNK - 1)/FS_CHUNK) * 8;
  float invN = 1.0f / (float)N;
  dim3 ablk(12,16);

  // 1) detect + weights + zero cnt/st/gctr/bhist + zero HS row N
  k_prep<<<33, B, 0, stream>>>((const unsigned short*)x, (const unsigned int*)ei,
                               flag, in_sizes[0], E, W1, W2, W3, W4,
                               Wt1b, Wt2b, Wt3b, W4f, cnt, stAll, HS, N);

  if (u16){
    unsigned short* csr = (unsigned short*)csrv;
    unsigned int* ec = (unsigned int*)ecv;
    // 2) degree count + PACKED edge compaction (4B/edge)
    k_cnt2p<<<gE2, B, 0, stream>>>(ei, flag, cnt, ec, E, N);
    // 3) rounded row allocation + wave-aggregated degree histogram
    k_emit2<unsigned short><<<nb, B, 0, stream>>>(cnt, gctr, rowst, cursor, dinv, csr, bhist, N);
    // 3b) bucket prefix
    k_bpre<<<1, 64, 0, stream>>>(bhist, bcur);
    // 4) CSR fill + XS build + degree-sorted perm scatter (wave-aggregated)
    k_fxp<<<gF8 + gXS + gPS, B, 0, stream>>>(ec, cursor, csr, E, N, gF8, gXS,
                                             x, flag, dinv, XS, cnt, bcur, perm);
    // 5) layer 1: degree-sorted 32-col gather + MFMA W1 + stats
    k_aggx<unsigned short><<<gL, B, 0, stream>>>((const uint4*)XS, rowst, cnt, csr, perm, dinv, Wt1b, Zb, stA, N);
    // 6..9) layers 2..3
    k_linm<<<gL, B, 0, stream>>>(Zb, Wt2b, stA, g1, be1, flag, dinv, HS, N, invN);
    k_agg<unsigned short><<<gA, ablk, 0, stream>>>((const uint4*)HS, rowst, cnt, csr, perm, dinv, (uint4*)Zb, stB, N);
    k_linm<<<gL, B, 0, stream>>>(Zb, Wt3b, stB, g2, be2, flag, dinv, HS, N, invN);
    k_agg<unsigned short><<<gA, ablk, 0, stream>>>((const uint4*)HS, rowst, cnt, csr, perm, dinv, (uint4*)Zb, stC, N);
    // 10..11) layer 4 + output
    k_lin4<<<gN, B, 0, stream>>>(Zb, W4f, stC, g3, be3, flag, dinv, hs2, N, invN);
    k_agg2<unsigned short><<<gN, B, 0, stream>>>((const float2*)hs2, rowst, cnt, csr, dinv, b4, flag, d_out, N);
  } else {
    int* csr = (int*)csrv;
    int* ec = (int*)ecv;
    k_cnt2<<<gE2, B, 0, stream>>>(ei, flag, cnt, ec, E, N);
    k_emit2<int><<<nb, B, 0, stream>>>(cnt, gctr, rowst, cursor, dinv, csr, bhist, N);
    k_bpre<<<1, 64, 0, stream>>>(bhist, bcur);
    k_fx<<<gF8 + gXS + gPS, B, 0, stream>>>(ec, cursor, csr, E, N, gF8, gXS,
                                            x, flag, dinv, XS, cnt, bcur, perm);
    k_aggx<int><<<gL, B, 0, stream>>>((const uint4*)XS, rowst, cnt, csr, perm, dinv, Wt1b, Zb, stA, N);
    k_linm<<<gL, B, 0, stream>>>(Zb, Wt2b, stA, g1, be1, flag, dinv, HS, N, invN);
    k_agg<int><<<gA, ablk, 0, stream>>>((const uint4*)HS, rowst, cnt, csr, perm, dinv, (uint4*)Zb, stB, N);
    k_linm<<<gL, B, 0, stream>>>(Zb, Wt3b, stB, g2, be2, flag, dinv, HS, N, invN);
    k_agg<int><<<gA, ablk, 0, stream>>>((const uint4*)HS, rowst, cnt, csr, perm, dinv, (uint4*)Zb, stC, N);
    k_lin4<<<gN, B, 0, stream>>>(Zb, W4f, stC, g3, be3, flag, dinv, hs2, N, invN);
    k_agg2<int><<<gN, B, 0, stream>>>((const float2*)hs2, rowst, cnt, csr, dinv, b4, flag, d_out, N);
  }
}

// Round 10
// 323.181 us; speedup vs baseline: 3.3137x; 1.1753x over previous
//
#include <hip/hip_runtime.h>
#include <hip/hip_bf16.h>

using bf16x8 = __attribute__((ext_vector_type(8))) short;
using f32x4  = __attribute__((ext_vector_type(4))) float;

#define FS_CHUNK 4096

// ---------- helpers ----------
__device__ __forceinline__ float ldf(const void* p, size_t i, float isf){
  if (isf > 0.5f) return ((const float*)p)[i];
  unsigned int u = ((unsigned int)((const unsigned short*)p)[i]) << 16;
  return __uint_as_float(u);
}
__device__ __forceinline__ unsigned short f2bf(float v){
  unsigned int u = __float_as_uint(v);
  u = (u + 0x7FFFu + ((u >> 16) & 1u)) >> 16;   // RNE
  return (unsigned short)u;
}
__device__ __forceinline__ unsigned int pk2(float a, float b){
  return (unsigned int)f2bf(a) | ((unsigned int)f2bf(b) << 16);
}
__device__ __forceinline__ float lo16(unsigned int u){ return __uint_as_float(u << 16); }
__device__ __forceinline__ float hi16(unsigned int u){ return __uint_as_float(u & 0xFFFF0000u); }

// load 8 CSR indices with one (u16) or two (int) vector loads; p must be 16B-aligned
template<typename IT>
__device__ __forceinline__ void load8idx(const IT* p, int* o){
  if (sizeof(IT) == 2){
    uint4 v = *(const uint4*)p;
    o[0] = (int)(v.x & 0xFFFFu); o[1] = (int)(v.x >> 16);
    o[2] = (int)(v.y & 0xFFFFu); o[3] = (int)(v.y >> 16);
    o[4] = (int)(v.z & 0xFFFFu); o[5] = (int)(v.z >> 16);
    o[6] = (int)(v.w & 0xFFFFu); o[7] = (int)(v.w >> 16);
  } else {
    int4 a = ((const int4*)p)[0];
    int4 c = ((const int4*)p)[1];
    o[0]=a.x; o[1]=a.y; o[2]=a.z; o[3]=a.w;
    o[4]=c.x; o[5]=c.y; o[6]=c.z; o[7]=c.w;
  }
}

__global__ void k_fill(unsigned short* o, unsigned short v, int n){
  int i = blockIdx.x*blockDim.x + threadIdx.x;
  if (i < n) o[i] = v;
}

// ---------- fused: dtype detect + weight convert (block 0) + zero cnt/st/gctr/HSrowN (blocks >0) ----------
__global__ void k_prep(const unsigned short* xh, const unsigned int* eu,
                       float* flag, int nelemX, long long E,
                       const void* W1, const void* W2, const void* W3, const void* W4,
                       unsigned short* __restrict__ Wt1, unsigned short* __restrict__ Wt2,
                       unsigned short* __restrict__ Wt3, float* __restrict__ W4f,
                       int* __restrict__ cnt, float* __restrict__ stAll,
                       unsigned short* __restrict__ HS, int n){
  int t = threadIdx.x;
  if (blockIdx.x > 0){
    if (blockIdx.x == 1 && t < 96) HS[(size_t)96*n + t] = 0;   // zero row n (dummy gather target)
    int total = n + 4609;                 // cnt[N] + 3x8x192 stats + gctr
    for (int i = (int)(blockIdx.x-1)*256 + t; i < total; i += (int)(gridDim.x-1)*256){
      if (i < n) cnt[i] = 0; else stAll[i - n] = 0.f;   // 0.0f bits == int 0
    }
    return;
  }
  __shared__ int sf32, si64;
  __shared__ float sisf;
  if (t == 0){ sf32 = 0; si64 = 1; }
  __syncthreads();
  {
    int i = 2*t;
    if (i < nelemX){
      unsigned e8 = (xh[i] >> 7) & 0xFFu;
      if (e8 >= 140u) sf32 = 1;
    }
    if ((long long)(2*t + 1) < 2*E){
      if (eu[2*t + 1] != 0u) si64 = 0;
    }
  }
  __syncthreads();
  if (t == 0){
    flag[0] = (float)sf32; flag[1] = (float)si64;
    sisf = (float)sf32;
  }
  __syncthreads();
  float isf = sisf;
  for (int q = t; q < 3072; q += 256){
    int nn = q >> 5, k = q & 31;
    Wt1[q] = f2bf(ldf(W1, (size_t)96*k + nn, isf));
  }
  for (int q = t; q < 9216; q += 256){
    int nn = q/96, k = q - 96*nn;
    Wt2[q] = f2bf(ldf(W2, (size_t)96*k + nn, isf));
    Wt3[q] = f2bf(ldf(W3, (size_t)96*k + nn, isf));
  }
  if (t < 192) W4f[t] = ldf(W4, t, isf);
}

// ---------- degree count + edge compaction, u16-PACKED (dst<<16 | src), 4B/edge ----------
__global__ void k_cnt2p(const int* __restrict__ ei, const float* __restrict__ flag,
                        int* __restrict__ cnt, unsigned int* __restrict__ ec,
                        long long E, int n){
  long long i = (long long)blockIdx.x*blockDim.x + threadIdx.x;  // handles edges 2i, 2i+1
  long long i0 = 2*i;
  if (i0 >= E) return;
  bool i64 = (flag[1] > 0.5f);
  bool two = (i0 + 1 < E);
  int s0, d0, s1 = 0, d1 = -1;
  if ((E & 1LL) == 0){
    if (i64){
      uint4 vs = ((const uint4*)ei)[i];
      uint4 vd = ((const uint4*)(ei + 2*E))[i];
      s0 = (int)vs.x; s1 = (int)vs.z; d0 = (int)vd.x; d1 = (int)vd.z;
    } else {
      int2 vs = ((const int2*)ei)[i];
      int2 vd = ((const int2*)(ei + E))[i];
      s0 = vs.x; s1 = vs.y; d0 = vd.x; d1 = vd.y;
    }
  } else {
    if (i64){ s0 = ei[2*i0]; d0 = ei[2*E + 2*i0];
              if (two){ s1 = ei[2*i0+2]; d1 = ei[2*E + 2*i0 + 2]; } }
    else    { s0 = ei[i0];   d0 = ei[E + i0];
              if (two){ s1 = ei[i0+1];   d1 = ei[E + i0 + 1]; } }
  }
  bool ok0 = ((unsigned)s0 < (unsigned)n) && ((unsigned)d0 < (unsigned)n);
  bool ok1 = two && ((unsigned)s1 < (unsigned)n) && ((unsigned)d1 < (unsigned)n);
  unsigned p0 = ok0 ? (((unsigned)d0 << 16) | (unsigned)s0) : 0xFFFFFFFFu;
  unsigned p1 = ok1 ? (((unsigned)d1 << 16) | (unsigned)s1) : 0xFFFFFFFFu;
  if (two){
    uint2 o; o.x = p0; o.y = p1;
    ((uint2*)ec)[i] = o;
  } else {
    ec[i0] = p0;
  }
  if (ok0) atomicAdd(&cnt[d0], 1);
  if (ok1) atomicAdd(&cnt[d1], 1);
}

// ---------- degree count + edge compaction, int pairs (big-N path) ----------
__global__ void k_cnt2(const int* __restrict__ ei, const float* __restrict__ flag,
                       int* __restrict__ cnt, int* __restrict__ ec,
                       long long E, int n){
  long long i = (long long)blockIdx.x*blockDim.x + threadIdx.x;
  long long i0 = 2*i;
  if (i0 >= E) return;
  bool i64 = (flag[1] > 0.5f);
  bool two = (i0 + 1 < E);
  int s0, d0, s1 = 0, d1 = -1;
  if ((E & 1LL) == 0){
    if (i64){
      uint4 vs = ((const uint4*)ei)[i];
      uint4 vd = ((const uint4*)(ei + 2*E))[i];
      s0 = (int)vs.x; s1 = (int)vs.z; d0 = (int)vd.x; d1 = (int)vd.z;
    } else {
      int2 vs = ((const int2*)ei)[i];
      int2 vd = ((const int2*)(ei + E))[i];
      s0 = vs.x; s1 = vs.y; d0 = vd.x; d1 = vd.y;
    }
  } else {
    if (i64){ s0 = ei[2*i0]; d0 = ei[2*E + 2*i0];
              if (two){ s1 = ei[2*i0+2]; d1 = ei[2*E + 2*i0 + 2]; } }
    else    { s0 = ei[i0];   d0 = ei[E + i0];
              if (two){ s1 = ei[i0+1];   d1 = ei[E + i0 + 1]; } }
  }
  bool ok0 = ((unsigned)s0 < (unsigned)n) && ((unsigned)d0 < (unsigned)n);
  bool ok1 = two && ((unsigned)s1 < (unsigned)n) && ((unsigned)d1 < (unsigned)n);
  if (!ok0){ s0 = -1; d0 = -1; }
  if (!ok1){ s1 = -1; d1 = -1; }
  if (two){
    int4 o; o.x = s0; o.y = d0; o.z = s1; o.w = d1;
    ((int4*)ec)[i] = o;
  } else {
    int2 o; o.x = s0; o.y = d0;
    ((int2*)ec)[i0] = o;
  }
  if (ok0) atomicAdd(&cnt[d0], 1);
  if (ok1) atomicAdd(&cnt[d1], 1);
}

// ---------- row allocation with degree rounded to multiple of 8; pad slots -> dummy idx n ----------
template<typename IT>
__global__ void k_emit2(const int* __restrict__ cnt, int* __restrict__ gctr,
                        int* __restrict__ rowst, int* __restrict__ cursor,
                        float* __restrict__ dinv, IT* __restrict__ csr, int n){
  int i = blockIdx.x*256 + threadIdx.x;
  int lane = threadIdx.x & 63;
  int v  = (i < n) ? cnt[i] : 0;
  int rv = (v + 7) & ~7;                  // rounded allocation
  int s = rv;
  #pragma unroll
  for (int off = 1; off < 64; off <<= 1){
    int u = __shfl_up(s, off, 64);
    if (lane >= off) s += u;
  }
  int wtot = __shfl(s, 63, 64);
  int base = 0;
  if (lane == 63) base = atomicAdd(gctr, wtot);
  base = __shfl(base, 63, 64);
  if (i < n){
    int r = base + s - rv;
    rowst[i]  = r;
    cursor[i] = r;
    dinv[i]   = rsqrtf((float)(1 + v));
    for (int p = r + v; p < r + rv; ++p) csr[p] = (IT)n;   // dummy -> zero row
  }
}

// ---------- merged: XCD-partitioned slot fill from PACKED ec (4 edges/uint4) + XS build ----------
__global__ __launch_bounds__(256) void k_fxp(const unsigned int* __restrict__ ec,
      int* __restrict__ cursor, unsigned short* __restrict__ csr,
      long long E, int n, int gF8,
      const void* __restrict__ x, const float* __restrict__ flag,
      const float* __restrict__ dinv, unsigned short* __restrict__ XS){
  int t = threadIdx.x;
  if ((int)blockIdx.x < gF8){
    int part = blockIdx.x & 7;
    long long base = (long long)(blockIdx.x >> 3) * FS_CHUNK;
    int pl = (int)(((long long)n *  part     ) >> 3);
    int pr = (int)(((long long)n * (part + 1)) >> 3);
    long long lim = base + FS_CHUNK < E ? base + FS_CHUNK : E;
    for (long long i = base + 4*t; i < lim; i += 1024){
      uint4 v = ((const uint4*)ec)[i >> 2];          // edges i..i+3 packed (dst<<16|src)
      { int d = (int)(v.x >> 16);
        if (d >= pl && d < pr){ int p = atomicAdd(&cursor[d], 1); csr[p] = (unsigned short)(v.x & 0xFFFFu); } }
      if (i + 1 < lim){ int d = (int)(v.y >> 16);
        if (d >= pl && d < pr){ int p = atomicAdd(&cursor[d], 1); csr[p] = (unsigned short)(v.y & 0xFFFFu); } }
      if (i + 2 < lim){ int d = (int)(v.z >> 16);
        if (d >= pl && d < pr){ int p = atomicAdd(&cursor[d], 1); csr[p] = (unsigned short)(v.z & 0xFFFFu); } }
      if (i + 3 < lim){ int d = (int)(v.w >> 16);
        if (d >= pl && d < pr){ int p = atomicAdd(&cursor[d], 1); csr[p] = (unsigned short)(v.w & 0xFFFFu); } }
    }
    return;
  }
  int q = (int)(blockIdx.x - gF8)*256 + t;
  if (q < 4*(n+1)){
    int node = q >> 2, part = q & 3;
    uint4 o;
    if (node < n){
      float isf = flag[0];
      float di = dinv[node];
      if (isf > 0.5f){
        const float* xr = (const float*)x + (size_t)32*node + 8*part;
        o.x = pk2(xr[0]*di, xr[1]*di); o.y = pk2(xr[2]*di, xr[3]*di);
        o.z = pk2(xr[4]*di, xr[5]*di); o.w = pk2(xr[6]*di, xr[7]*di);
      } else {
        uint4 v = ((const uint4*)x)[(size_t)4*node + part];
        o.x = pk2(lo16(v.x)*di, hi16(v.x)*di);
        o.y = pk2(lo16(v.y)*di, hi16(v.y)*di);
        o.z = pk2(lo16(v.z)*di, hi16(v.z)*di);
        o.w = pk2(lo16(v.w)*di, hi16(v.w)*di);
      }
    } else { o.x = o.y = o.z = o.w = 0u; }        // zero row n (dummy gather target)
    ((uint4*)XS)[q] = o;
  }
}

// ---------- merged fill + XS build, int path (big N) ----------
__global__ __launch_bounds__(256) void k_fx(const int* __restrict__ ec,
      int* __restrict__ cursor, int* __restrict__ csr,
      long long E, int n, int gF8,
      const void* __restrict__ x, const float* __restrict__ flag,
      const float* __restrict__ dinv, unsigned short* __restrict__ XS){
  int t = threadIdx.x;
  if ((int)blockIdx.x < gF8){
    int part = blockIdx.x & 7;
    long long base = (long long)(blockIdx.x >> 3) * FS_CHUNK;
    int pl = (int)(((long long)n *  part     ) >> 3);
    int pr = (int)(((long long)n * (part + 1)) >> 3);
    long long lim = base + FS_CHUNK < E ? base + FS_CHUNK : E;
    for (long long i = base + 2*t; i < lim; i += 512){
      int4 v = ((const int4*)ec)[i >> 1];          // edges i:(x,y)  i+1:(z,w)
      if (v.y >= pl && v.y < pr && (unsigned)v.x < (unsigned)n){
        int p = atomicAdd(&cursor[v.y], 1);
        csr[p] = v.x;
      }
      if (i + 1 < lim && v.w >= pl && v.w < pr && (unsigned)v.z < (unsigned)n){
        int p = atomicAdd(&cursor[v.w], 1);
        csr[p] = v.z;
      }
    }
    return;
  }
  int q = (int)(blockIdx.x - gF8)*256 + t;
  if (q < 4*(n+1)){
    int node = q >> 2, part = q & 3;
    uint4 o;
    if (node < n){
      float isf = flag[0];
      float di = dinv[node];
      if (isf > 0.5f){
        const float* xr = (const float*)x + (size_t)32*node + 8*part;
        o.x = pk2(xr[0]*di, xr[1]*di); o.y = pk2(xr[2]*di, xr[3]*di);
        o.z = pk2(xr[4]*di, xr[5]*di); o.w = pk2(xr[6]*di, xr[7]*di);
      } else {
        uint4 v = ((const uint4*)x)[(size_t)4*node + part];
        o.x = pk2(lo16(v.x)*di, hi16(v.x)*di);
        o.y = pk2(lo16(v.y)*di, hi16(v.y)*di);
        o.z = pk2(lo16(v.z)*di, hi16(v.z)*di);
        o.w = pk2(lo16(v.w)*di, hi16(v.w)*di);
      }
    } else { o.x = o.y = o.z = o.w = 0u; }
    ((uint4*)XS)[q] = o;
  }
}

#define ACC8(v) { a0+=lo16((v).x); a1+=hi16((v).x); a2+=lo16((v).y); a3+=hi16((v).y); \
                  a4+=lo16((v).z); a5+=hi16((v).z); a6+=lo16((v).w); a7+=hi16((v).w); }

// ---------- layer 1: gather-sum XS (32 cols, padded CSR, vector idx) + dinv + MFMA W1 + stats ----------
template<typename IT>
__global__ __launch_bounds__(256) void k_aggx(const uint4* __restrict__ xs4,
      const int* __restrict__ rowst, const int* __restrict__ cnt,
      const IT* __restrict__ csr, const float* __restrict__ dinv,
      const unsigned short* __restrict__ Wt1b,
      unsigned short* __restrict__ Zb, float* __restrict__ stout, int n){
  __shared__ __align__(16) unsigned short Xs[64][40];
  __shared__ __align__(16) unsigned short Wt[96][40];
  __shared__ float bs[96], bq[96];
  int t = threadIdx.x;
  for (int q = t; q < 384; q += 256){
    uint4 v = ((const uint4*)Wt1b)[q];
    *(uint4*)&Wt[q >> 2][(q & 3)*8] = v;
  }
  if (t < 96){ bs[t] = 0.f; bq[t] = 0.f; }
  int g = t & 3, ty = t >> 2;
  int node = blockIdx.x*64 + ty;
  float a0=0.f,a1=0.f,a2=0.f,a3=0.f,a4=0.f,a5=0.f,a6=0.f,a7=0.f;
  if (node < n){
    uint4 v = xs4[(size_t)node*4 + g];           // self-loop contribution
    ACC8(v);
    int bq_ = rowst[node];
    int bnd = bq_ + ((cnt[node] + 7) & ~7);      // padded, uniform batches of 8
    for (int j = bq_; j < bnd; j += 8){
      int ix[8];
      load8idx<IT>(csr + j, ix);
      uint4 v0 = xs4[(size_t)ix[0]*4 + g];
      uint4 v1 = xs4[(size_t)ix[1]*4 + g];
      uint4 v2 = xs4[(size_t)ix[2]*4 + g];
      uint4 v3 = xs4[(size_t)ix[3]*4 + g];
      uint4 v4 = xs4[(size_t)ix[4]*4 + g];
      uint4 v5 = xs4[(size_t)ix[5]*4 + g];
      uint4 v6 = xs4[(size_t)ix[6]*4 + g];
      uint4 v7 = xs4[(size_t)ix[7]*4 + g];
      ACC8(v0); ACC8(v1); ACC8(v2); ACC8(v3);
      ACC8(v4); ACC8(v5); ACC8(v6); ACC8(v7);
    }
    float di = dinv[node];
    a0*=di; a1*=di; a2*=di; a3*=di; a4*=di; a5*=di; a6*=di; a7*=di;
  }
  uint4 o;
  o.x = pk2(a0,a1); o.y = pk2(a2,a3); o.z = pk2(a4,a5); o.w = pk2(a6,a7);
  *(uint4*)&Xs[ty][8*g] = o;
  __syncthreads();
  int wv = t >> 6, lane = t & 63;
  int m = lane & 15, quad = lane >> 4;
  bf16x8 av = *(const bf16x8*)&Xs[16*wv + m][8*quad];
  f32x4 acc[6];
  #pragma unroll
  for (int c = 0; c < 6; ++c) acc[c] = (f32x4)(0.f);
  #pragma unroll
  for (int c = 0; c < 6; ++c){
    bf16x8 bv = *(const bf16x8*)&Wt[16*c + m][8*quad];
    acc[c] = __builtin_amdgcn_mfma_f32_16x16x32_bf16(av, bv, acc[c], 0, 0, 0);
  }
  int rowbase = blockIdx.x*64 + 16*wv + 4*quad;
  #pragma unroll
  for (int c = 0; c < 6; ++c){
    int col = 16*c + m;
    float s = 0.f, q = 0.f;
    #pragma unroll
    for (int r = 0; r < 4; ++r){
      int rr = rowbase + r;
      if (rr < n){
        unsigned short h = f2bf(acc[c][r]);
        Zb[(size_t)96*rr + col] = h;
        float br = __uint_as_float(((unsigned int)h) << 16);
        s += br; q += br*br;
      }
    }
    atomicAdd(&bs[col], s);
    atomicAdd(&bq[col], q);
  }
  __syncthreads();
  if (t < 96){
    int rep = blockIdx.x & 7;
    atomicAdd(&stout[192*rep + t],      bs[t]);
    atomicAdd(&stout[192*rep + 96 + t], bq[t]);
  }
}

// ---------- CSR gather aggregation (bf16, 96 cols, padded CSR, vector idx) + fused BN stats ----------
template<typename IT>
__global__ __launch_bounds__(192) void k_agg(const uint4* __restrict__ hsr,
      const int* __restrict__ rowst, const int* __restrict__ cnt,
      const IT* __restrict__ csr,
      const float* __restrict__ dinv, uint4* __restrict__ zb4,
      float* __restrict__ stout, int n){
  __shared__ float ls[16][97], lq[16][97];
  int g = threadIdx.x, ty = threadIdx.y;
  int t = ty*12 + g;
  int node = blockIdx.x*16 + ty;
  float r[8];
  if (node < n){
    uint4 v = hsr[(size_t)node*12 + g];
    float a0 = lo16(v.x), a1 = hi16(v.x), a2 = lo16(v.y), a3 = hi16(v.y);
    float a4 = lo16(v.z), a5 = hi16(v.z), a6 = lo16(v.w), a7 = hi16(v.w);
    int bq_ = rowst[node];
    int bnd = bq_ + ((cnt[node] + 7) & ~7);      // padded, uniform batches of 8
    for (int j = bq_; j < bnd; j += 8){
      int ix[8];
      load8idx<IT>(csr + j, ix);
      uint4 v0 = hsr[(size_t)ix[0]*12 + g];
      uint4 v1 = hsr[(size_t)ix[1]*12 + g];
      uint4 v2 = hsr[(size_t)ix[2]*12 + g];
      uint4 v3 = hsr[(size_t)ix[3]*12 + g];
      uint4 v4 = hsr[(size_t)ix[4]*12 + g];
      uint4 v5 = hsr[(size_t)ix[5]*12 + g];
      uint4 v6 = hsr[(size_t)ix[6]*12 + g];
      uint4 v7 = hsr[(size_t)ix[7]*12 + g];
      ACC8(v0); ACC8(v1); ACC8(v2); ACC8(v3);
      ACC8(v4); ACC8(v5); ACC8(v6); ACC8(v7);
    }
    float di = dinv[node];
    uint4 o;
    o.x = pk2(a0*di, a1*di);
    o.y = pk2(a2*di, a3*di);
    o.z = pk2(a4*di, a5*di);
    o.w = pk2(a6*di, a7*di);
    zb4[(size_t)node*12 + g] = o;
    r[0]=lo16(o.x); r[1]=hi16(o.x); r[2]=lo16(o.y); r[3]=hi16(o.y);
    r[4]=lo16(o.z); r[5]=hi16(o.z); r[6]=lo16(o.w); r[7]=hi16(o.w);
  } else {
    #pragma unroll
    for (int jj = 0; jj < 8; ++jj) r[jj] = 0.f;
  }
  #pragma unroll
  for (int jj = 0; jj < 8; ++jj){
    ls[ty][8*g + jj] = r[jj];
    lq[ty][8*g + jj] = r[jj]*r[jj];
  }
  __syncthreads();
  if (t < 96){
    float s = 0.f, q = 0.f;
    #pragma unroll
    for (int rr = 0; rr < 16; ++rr){ s += ls[rr][t]; q += lq[rr][t]; }
    int rep = blockIdx.x & 7;
    atomicAdd(&stout[192*rep + t],      s);
    atomicAdd(&stout[192*rep + 96 + t], q);
  }
}

// ---------- MFMA mid layer ----------
__global__ __launch_bounds__(256) void k_linm(const unsigned short* __restrict__ zb,
      const unsigned short* __restrict__ Wtb, const float* __restrict__ st,
      const void* __restrict__ gam, const void* __restrict__ bet,
      const float* __restrict__ flag, const float* __restrict__ dinv,
      unsigned short* __restrict__ HS, int n, float invN){
  __shared__ float sa[96], sc[96];
  __shared__ __align__(16) unsigned short Ys[64][104];
  __shared__ __align__(16) unsigned short Wt[96][104];
  int t = threadIdx.x;
  if (t < 96){
    float ssum = 0.f, qsum = 0.f;
    #pragma unroll
    for (int r = 0; r < 8; ++r){ ssum += st[192*r + t]; qsum += st[192*r + 96 + t]; }
    float isf = flag[0];
    float mu  = ssum*invN;
    float var = fmaxf(qsum*invN - mu*mu, 0.f);
    float istd = rsqrtf(var + 1e-5f);
    float a = ldf(gam, t, isf)*istd;
    sa[t] = a; sc[t] = ldf(bet, t, isf) - mu*a;
  }
  for (int q = t; q < 1152; q += 256){
    uint4 v = ((const uint4*)Wtb)[q];
    *(uint4*)&Wt[q/12][8*(q - 12*(q/12))] = v;
  }
  __syncthreads();
  {
    int row = t >> 2, part = t & 3;
    int node = blockIdx.x*64 + row;
    if (node < n){
      const uint4* zr = (const uint4*)(zb + (size_t)96*node) + 3*part;
      #pragma unroll
      for (int q = 0; q < 3; ++q){
        uint4 zz = zr[q];
        int k = 24*part + 8*q;
        float y0 = fmaxf(lo16(zz.x)*sa[k]   + sc[k],   0.f);
        float y1 = fmaxf(hi16(zz.x)*sa[k+1] + sc[k+1], 0.f);
        float y2 = fmaxf(lo16(zz.y)*sa[k+2] + sc[k+2], 0.f);
        float y3 = fmaxf(hi16(zz.y)*sa[k+3] + sc[k+3], 0.f);
        float y4 = fmaxf(lo16(zz.z)*sa[k+4] + sc[k+4], 0.f);
        float y5 = fmaxf(hi16(zz.z)*sa[k+5] + sc[k+5], 0.f);
        float y6 = fmaxf(lo16(zz.w)*sa[k+6] + sc[k+6], 0.f);
        float y7 = fmaxf(hi16(zz.w)*sa[k+7] + sc[k+7], 0.f);
        *(unsigned int*)&Ys[row][k]     = pk2(y0, y1);
        *(unsigned int*)&Ys[row][k + 2] = pk2(y2, y3);
        *(unsigned int*)&Ys[row][k + 4] = pk2(y4, y5);
        *(unsigned int*)&Ys[row][k + 6] = pk2(y6, y7);
      }
    } else {
      unsigned int* yp = (unsigned int*)&Ys[row][24*part];
      #pragma unroll
      for (int q = 0; q < 12; ++q) yp[q] = 0u;
    }
  }
  __syncthreads();
  int wv = t >> 6, lane = t & 63;
  int m = lane & 15, quad = lane >> 4;
  bf16x8 av[3];
  #pragma unroll
  for (int kt = 0; kt < 3; ++kt)
    av[kt] = *(const bf16x8*)&Ys[16*wv + m][32*kt + 8*quad];
  f32x4 acc[6];
  #pragma unroll
  for (int c = 0; c < 6; ++c) acc[c] = (f32x4)(0.f);
  #pragma unroll
  for (int c = 0; c < 6; ++c){
    const unsigned short* wrow = &Wt[16*c + m][8*quad];
    #pragma unroll
    for (int kt = 0; kt < 3; ++kt){
      bf16x8 bv = *(const bf16x8*)(wrow + 32*kt);
      acc[c] = __builtin_amdgcn_mfma_f32_16x16x32_bf16(av[kt], bv, acc[c], 0, 0, 0);
    }
  }
  int rowbase = blockIdx.x*64 + 16*wv + 4*quad;
  float div[4];
  #pragma unroll
  for (int r = 0; r < 4; ++r){ int rr = rowbase + r; div[r] = (rr < n) ? dinv[rr] : 0.f; }
  #pragma unroll
  for (int c = 0; c < 6; ++c){
    int col = 16*c + m;
    #pragma unroll
    for (int r = 0; r < 4; ++r){
      int rr = rowbase + r;
      if (rr < n) HS[(size_t)96*rr + col] = f2bf(acc[c][r]*div[r]);
    }
  }
}

// ---------- layer 4 (96->2, VALU) ----------
__global__ __launch_bounds__(256) void k_lin4(const unsigned short* __restrict__ zb,
      const float* __restrict__ Wf, const float* __restrict__ st,
      const void* __restrict__ gam, const void* __restrict__ bet,
      const float* __restrict__ flag, const float* __restrict__ dinv,
      float* __restrict__ hs2, int n, float invN){
  __shared__ float sa[96], sc[96];
  int t = threadIdx.x;
  if (t < 96){
    float ssum = 0.f, qsum = 0.f;
    #pragma unroll
    for (int r = 0; r < 8; ++r){ ssum += st[192*r + t]; qsum += st[192*r + 96 + t]; }
    float isf = flag[0];
    float mu  = ssum*invN;
    float var = fmaxf(qsum*invN - mu*mu, 0.f);
    float istd = rsqrtf(var + 1e-5f);
    float a = ldf(gam, t, isf)*istd;
    sa[t] = a; sc[t] = ldf(bet, t, isf) - mu*a;
  }
  __syncthreads();
  int i = blockIdx.x*blockDim.x + t;
  if (i >= n) return;
  const uint4* zr = (const uint4*)(zb + (size_t)96*i);
  float a0 = 0.f, a1 = 0.f;
  #pragma unroll
  for (int q = 0; q < 12; ++q){
    uint4 zz = zr[q];
    int k = 8*q;
    float y;
    y = fmaxf(lo16(zz.x)*sa[k]   + sc[k],   0.f); a0 += y*Wf[2*k];    a1 += y*Wf[2*k+1];
    y = fmaxf(hi16(zz.x)*sa[k+1] + sc[k+1], 0.f); a0 += y*Wf[2*k+2];  a1 += y*Wf[2*k+3];
    y = fmaxf(lo16(zz.y)*sa[k+2] + sc[k+2], 0.f); a0 += y*Wf[2*k+4];  a1 += y*Wf[2*k+5];
    y = fmaxf(hi16(zz.y)*sa[k+3] + sc[k+3], 0.f); a0 += y*Wf[2*k+6];  a1 += y*Wf[2*k+7];
    y = fmaxf(lo16(zz.z)*sa[k+4] + sc[k+4], 0.f); a0 += y*Wf[2*k+8];  a1 += y*Wf[2*k+9];
    y = fmaxf(hi16(zz.z)*sa[k+5] + sc[k+5], 0.f); a0 += y*Wf[2*k+10]; a1 += y*Wf[2*k+11];
    y = fmaxf(lo16(zz.w)*sa[k+6] + sc[k+6], 0.f); a0 += y*Wf[2*k+12]; a1 += y*Wf[2*k+13];
    y = fmaxf(hi16(zz.w)*sa[k+7] + sc[k+7], 0.f); a0 += y*Wf[2*k+14]; a1 += y*Wf[2*k+15];
  }
  float di = dinv[i];
  hs2[(size_t)2*i]   = di*a0;
  hs2[(size_t)2*i+1] = di*a1;
}

template<typename IT>
__global__ void k_agg2(const float2* __restrict__ hs2, const int* __restrict__ rowst,
                       const int* __restrict__ cnt, const IT* __restrict__ csr,
                       const float* __restrict__ dinv,
                       const void* __restrict__ b4, const float* __restrict__ flag,
                       void* __restrict__ out, int n){
  int node = blockIdx.x*blockDim.x + threadIdx.x;
  if (node >= n) return;
  float2 a = hs2[node];
  int b = rowst[node], e = b + cnt[node];   // real count only (no padded reads)
  int j = b;
  for (; j + 3 < e; j += 4){
    float2 v0 = hs2[(size_t)csr[j]];
    float2 v1 = hs2[(size_t)csr[j+1]];
    float2 v2 = hs2[(size_t)csr[j+2]];
    float2 v3 = hs2[(size_t)csr[j+3]];
    a.x += v0.x + v1.x + v2.x + v3.x;
    a.y += v0.y + v1.y + v2.y + v3.y;
  }
  for (; j < e; ++j){
    float2 v = hs2[(size_t)csr[j]];
    a.x += v.x; a.y += v.y;
  }
  float isf = flag[0];
  float di = dinv[node];
  float v0 = a.x*di + ldf(b4, 0, isf);
  float v1 = a.y*di + ldf(b4, 1, isf);
  if (isf > 0.5f){
    ((float*)out)[(size_t)2*node]   = v0;
    ((float*)out)[(size_t)2*node+1] = v1;
  } else {
    ((unsigned short*)out)[(size_t)2*node]   = f2bf(v0);
    ((unsigned short*)out)[(size_t)2*node+1] = f2bf(v1);
  }
}

extern "C" void kernel_launch(void* const* d_in, const int* in_sizes, int n_in,
                              void* d_out, int out_size, void* d_ws, size_t ws_size,
                              hipStream_t stream)
{
  const int B = 256;
  unsigned short* outh = (unsigned short*)d_out;

  if (n_in < 16){
    k_fill<<<(out_size+B-1)/B, B, 0, stream>>>(outh, 0x3F40u, out_size); return;
  }
  const int N = in_sizes[0] / 32;
  const long long E = in_sizes[1] / 2;
  if (in_sizes[0] % 32 != 0 || out_size != 2*N){
    k_fill<<<(out_size+B-1)/B, B, 0, stream>>>(outh, 0x3F60u, out_size); return;
  }
  const bool u16 = (N < 65536);

  // ---- workspace layout ----
  size_t Npad = ((size_t)N + 3) & ~(size_t)3;
  float* ws   = (float*)d_ws;
  float* dinv = ws;                               // Npad
  float* hs2  = dinv + Npad;                      // 2N
  float* flag = hs2 + (size_t)2*N;                // 4
  float* stAll= flag + 4;                         // 4608 stats + 1 gctr (+3 pad)
  float* W4f  = stAll + 4612;                     // 192
  unsigned short* Wt1b = (unsigned short*)(W4f + 192);
  unsigned short* Wt2b = Wt1b + 3072;
  unsigned short* Wt3b = Wt2b + 9216;
  int* cnt    = (int*)(Wt3b + 9216);              // N
  int* cursor = cnt + N;                          // N
  int* rowst  = cursor + N;                       // N
  uintptr_t cs_ = (uintptr_t)(rowst + N);
  cs_ = (cs_ + 15) & ~(uintptr_t)15;              // 16B-align csr for vector idx loads
  void* csrv  = (void*)cs_;                       // E + 8N entries (padded alloc)
  size_t csrCap = (size_t)E + 8*(size_t)N;
  size_t csrBytes = csrCap * (u16 ? 2 : 4);
  uintptr_t hp_ = cs_ + csrBytes;
  hp_ = (hp_ + 15) & ~(uintptr_t)15;
  unsigned short* HS = (unsigned short*)hp_;      // 96*(N+1) bf16 (row N = zeros; also hosts XS = 32*(N+1))
  unsigned short* Zb = HS + (size_t)96*(N+1);     // 96N bf16
  uintptr_t ec_ = (uintptr_t)(Zb + (size_t)96*N);
  ec_ = (ec_ + 15) & ~(uintptr_t)15;
  void* ecv = (void*)ec_;                         // u16: E+4 uints packed; else 2E ints

  size_t ecBytes = u16 ? ((size_t)E + 4)*4 : ((size_t)2*E + 4)*4;
  size_t needB = (ec_ + ecBytes - (uintptr_t)d_ws) + 64;
  if (ws_size < needB){
    k_fill<<<(out_size+B-1)/B, B, 0, stream>>>(outh, 0x3F00u, out_size); return;
  }

  unsigned short* XS = HS;                        // 32*(N+1) bf16, reuses HS region

  const void* x  = d_in[0];
  const int*  ei = (const int*)d_in[1];
  const void* W1 = d_in[2];
  const void* g1 = d_in[4];  const void* be1 = d_in[5];
  const void* W2 = d_in[6];
  const void* g2 = d_in[8];  const void* be2 = d_in[9];
  const void* W3 = d_in[10];
  const void* g3 = d_in[12]; const void* be3 = d_in[13];
  const void* W4 = d_in[14];
  const void* b4 = d_in[15];

  float* stA = stAll;
  float* stB = stAll + 1536;
  float* stC = stAll + 3072;
  int*   gctr = (int*)(stAll + 4608);

  int gN  = (N + B - 1)/B;
  long long hE = (E + 1)/2;
  int gE2 = (int)((hE + B - 1)/B); if (gE2 < 1) gE2 = 1;
  int nb  = (N + 255)/256;
  int gA  = (N + 15)/16;
  int gL  = (N + 63)/64;
  int gXS = (4*(N+1) + 255)/256;
  int gF8 = (int)((E + FS_CHUNK - 1)/FS_CHUNK) * 8;
  float invN = 1.0f / (float)N;
  dim3 ablk(12,16);

  // 1) detect + weights + zero cnt/st/gctr + zero HS row N
  k_prep<<<33, B, 0, stream>>>((const unsigned short*)x, (const unsigned int*)ei,
                               flag, in_sizes[0], E, W1, W2, W3, W4,
                               Wt1b, Wt2b, Wt3b, W4f, cnt, stAll, HS, N);

  if (u16){
    unsigned short* csr = (unsigned short*)csrv;
    unsigned int* ec = (unsigned int*)ecv;
    // 2) degree count + PACKED edge compaction (4B/edge)
    k_cnt2p<<<gE2, B, 0, stream>>>(ei, flag, cnt, ec, E, N);
    // 3) rounded row allocation -> rowst, cursor, dinv, pad slots
    k_emit2<unsigned short><<<nb, B, 0, stream>>>(cnt, gctr, rowst, cursor, dinv, csr, N);
    // 4) CSR fill (packed ec, 4 edges/uint4) + XS build incl zero row N
    k_fxp<<<gF8 + gXS, B, 0, stream>>>(ec, cursor, csr, E, N, gF8, x, flag, dinv, XS);
    // 5) layer 1: 32-col gather (padded, vector idx) + MFMA W1 + stats
    k_aggx<unsigned short><<<gL, B, 0, stream>>>((const uint4*)XS, rowst, cnt, csr, dinv, Wt1b, Zb, stA, N);
    // 6..9) layers 2..3
    k_linm<<<gL, B, 0, stream>>>(Zb, Wt2b, stA, g1, be1, flag, dinv, HS, N, invN);
    k_agg<unsigned short><<<gA, ablk, 0, stream>>>((const uint4*)HS, rowst, cnt, csr, dinv, (uint4*)Zb, stB, N);
    k_linm<<<gL, B, 0, stream>>>(Zb, Wt3b, stB, g2, be2, flag, dinv, HS, N, invN);
    k_agg<unsigned short><<<gA, ablk, 0, stream>>>((const uint4*)HS, rowst, cnt, csr, dinv, (uint4*)Zb, stC, N);
    // 10..11) layer 4 + output
    k_lin4<<<gN, B, 0, stream>>>(Zb, W4f, stC, g3, be3, flag, dinv, hs2, N, invN);
    k_agg2<unsigned short><<<gN, B, 0, stream>>>((const float2*)hs2, rowst, cnt, csr, dinv, b4, flag, d_out, N);
  } else {
    int* csr = (int*)csrv;
    int* ec = (int*)ecv;
    k_cnt2<<<gE2, B, 0, stream>>>(ei, flag, cnt, ec, E, N);
    k_emit2<int><<<nb, B, 0, stream>>>(cnt, gctr, rowst, cursor, dinv, csr, N);
    k_fx<<<gF8 + gXS, B, 0, stream>>>(ec, cursor, csr, E, N, gF8, x, flag, dinv, XS);
    k_aggx<int><<<gL, B, 0, stream>>>((const uint4*)XS, rowst, cnt, csr, dinv, Wt1b, Zb, stA, N);
    k_linm<<<gL, B, 0, stream>>>(Zb, Wt2b, stA, g1, be1, flag, dinv, HS, N, invN);
    k_agg<int><<<gA, ablk, 0, stream>>>((const uint4*)HS, rowst, cnt, csr, dinv, (uint4*)Zb, stB, N);
    k_linm<<<gL, B, 0, stream>>>(Zb, Wt3b, stB, g2, be2, flag, dinv, HS, N, invN);
    k_agg<int><<<gA, ablk, 0, stream>>>((const uint4*)HS, rowst, cnt, csr, dinv, (uint4*)Zb, stC, N);
    k_lin4<<<gN, B, 0, stream>>>(Zb, W4f, stC, g3, be3, flag, dinv, hs2, N, invN);
    k_agg2<int><<<gN, B, 0, stream>>>((const float2*)hs2, rowst, cnt, csr, dinv, b4, flag, d_out, N);
  }
}